// Round 12
// baseline (43275.012 us; speedup 1.0000x reference)
//
#include <hip/hip_runtime.h>

#define NBLK 256
#define NTHR 1024

constexpr int kNMel = 80, kArnn = 1024, kAdim = 128, kEmb = 512, kPre = 256;
constexpr int kNF = 32, kKS = 31, kB = 32, kNctx = 512, kT = 500, kPad = 15;

constexpr int KT_A = 56;   // 1792/32 k-tiles (aLSTM: 256 prenet + 512 actx + 1024 ah)
constexpr int KT_D = 80;   // 2560/32 k-tiles (dLSTM: 1024 ah + 512 actx + 1024 dh)
constexpr int KT_ALL = KT_A + KT_D;

// ---- workspace layout (float offsets); GMB last so it is optional ----
constexpr int OFF_PREB   = 0;                                    // bf16 [500][32][256]
constexpr int OFF_PROCMB = OFF_PREB + kT * kB * kPre / 2;        // bf16 [32*512][128]
constexpr int OFF_QWTB   = OFF_PROCMB + kB * kNctx * kAdim / 2;  // bf16 [128][1024]
constexpr int OFF_LWT    = OFF_QWTB + kAdim * kArnn / 2;         // f32 [128*33]
constexpr int OFF_STATE  = OFF_LWT + kAdim * 33;
constexpr int OFF_AHB    = OFF_STATE;                            // bf16 [2][32][1024]
constexpr int OFF_DHB    = OFF_AHB + 2 * kB * kArnn / 2;         // bf16 [2][32][1024]
constexpr int OFF_DH     = OFF_DHB + 2 * kB * kArnn / 2;         // f32 [2][32][1024]
constexpr int OFF_AC     = OFF_DH + 2 * kB * kArnn;              // f32 [32][1024]
constexpr int OFF_DC     = OFF_AC + kB * kArnn;
constexpr int OFF_ACTX   = OFF_DC + kB * kArnn;                  // f32 [32][512]
constexpr int OFF_AW     = OFF_ACTX + kB * kEmb;                 // f32 [32][512]
constexpr int OFF_AWC    = OFF_AW + kB * kNctx;
constexpr int OFF_PAW    = OFF_AWC + kB * kNctx;                 // block-private
constexpr int OFF_NUM    = OFF_PAW + kB * kNctx;                 // f32 [2][32][512]
constexpr int OFF_DEN    = OFF_NUM + 2 * kB * kEmb;              // f32 [2][32]
constexpr int OFF_END    = OFF_DEN + 2 * kB;
constexpr int STATE_SZ   = OFF_END - OFF_STATE;
// barrier region: one 128B line per word (per-block flags, wake replicas, init)
constexpr int OFF_BAR    = OFF_END;
constexpr int BAR_LINES  = 266;
constexpr int OFF_PAN    = OFF_BAR + BAR_LINES * 32;             // bf16 panels
constexpr int PAN_SZ     = NBLK * KT_ALL * 256;                  // floats
constexpr int OFF_GMB    = OFF_PAN + PAN_SZ;                     // bf16 [32*512][512] (optional)
constexpr int GMB_SZ     = kB * kNctx * kEmb / 2;

typedef __attribute__((ext_vector_type(4))) float fvec4;
typedef __attribute__((ext_vector_type(8))) short bh8_t;
typedef unsigned long long u64;
typedef unsigned short ushortt;

union U64u { u64 u; float2 f2; ushortt s[4]; };

union SMem {
  struct { ushortt xs[16][2048]; } x1;                               // 64 KB: per-wave 4 KB
  struct { float zra[8][2][64][4]; float zrd[8][2][64][4];
           float hb[2][32][4]; } x2;                                 // 33 KB overlay
  struct { float ahb_s[kArnn]; float vw_s[kAdim]; float psum[1024]; float q_s[kAdim];
           float aw_s[96]; float awc_s[96]; float cw[kNF * 2 * kKS];
           float loc_s[64 * 33]; float p_s[64]; float lwt[kAdim * 33];
           float dhc[kArnn + kEmb]; float pprj[126];
           ushortt pm[64 * kAdim]; } b;
  struct { float x8[8][80]; float h1[8][256]; } p;
  struct { float mem_s[4][512]; } m;
};

__device__ __forceinline__ float sigf(float x) { return 1.0f / (1.0f + __expf(-x)); }
__device__ __forceinline__ float tanhfast(float x) { return 1.0f - 2.0f / (__expf(2.0f * x) + 1.0f); }

__device__ __forceinline__ ushortt bf16rn(float f) {
  unsigned u = __float_as_uint(f);
  unsigned r = (u + 0x7FFFu + ((u >> 16) & 1u)) >> 16;
  return (ushortt)r;
}
__device__ __forceinline__ float bf2f(ushortt v) {
  return __uint_as_float((unsigned)v << 16);
}

// relaxed agent-scope atomics: cross-XCD coherent, no cache-invalidation side effects
__device__ __forceinline__ u64 ald64(const void* p) {
  return __hip_atomic_load((const u64*)p, __ATOMIC_RELAXED, __HIP_MEMORY_SCOPE_AGENT);
}
__device__ __forceinline__ float alf(const float* p) {
  return __hip_atomic_load(p, __ATOMIC_RELAXED, __HIP_MEMORY_SCOPE_AGENT);
}
__device__ __forceinline__ void asf(float* p, float v) {
  __hip_atomic_store(p, v, __ATOMIC_RELAXED, __HIP_MEMORY_SCOPE_AGENT);
}
__device__ __forceinline__ void as64(void* p, u64 v) {
  __hip_atomic_store((u64*)p, v, __ATOMIC_RELAXED, __HIP_MEMORY_SCOPE_AGENT);
}
__device__ __forceinline__ unsigned alu(const unsigned* p) {
  return __hip_atomic_load(p, __ATOMIC_RELAXED, __HIP_MEMORY_SCOPE_AGENT);
}
__device__ __forceinline__ void asu(unsigned* p, unsigned v) {
  __hip_atomic_store(p, v, __ATOMIC_RELAXED, __HIP_MEMORY_SCOPE_AGENT);
}

// heavyweight init barrier (acq/rel) — used twice, before the scan
__device__ __forceinline__ void gbar_full(unsigned* cnt, unsigned* gen, unsigned& genv) {
  __syncthreads();
  if (threadIdx.x == 0) {
    __threadfence();
    unsigned arrived = __hip_atomic_fetch_add(cnt, 1u, __ATOMIC_ACQ_REL, __HIP_MEMORY_SCOPE_AGENT) + 1u;
    if (arrived == (unsigned)NBLK) {
      __hip_atomic_store(cnt, 0u, __ATOMIC_RELAXED, __HIP_MEMORY_SCOPE_AGENT);
      __hip_atomic_fetch_add(gen, 1u, __ATOMIC_ACQ_REL, __HIP_MEMORY_SCOPE_AGENT);
    } else {
      while (__hip_atomic_load(gen, __ATOMIC_ACQUIRE, __HIP_MEMORY_SCOPE_AGENT) == genv) {
        __builtin_amdgcn_s_sleep(2);
      }
    }
    ++genv;
  }
  __syncthreads();
}

// lightweight scan barrier: per-block flag lines; block 0 sweeps, fans out wake gen
__device__ __forceinline__ void gbar_light(unsigned* bar, unsigned target, int bk, int tid) {
  asm volatile("s_waitcnt vmcnt(0) lgkmcnt(0)" ::: "memory");
  __syncthreads();
  if (bk == 0) {
    if (tid < 64) {
      if (tid == 0) asm volatile("s_waitcnt vmcnt(0)" ::: "memory");
      unsigned i0 = (unsigned)tid * 4, i1 = i0 + 1, i2 = i0 + 2, i3 = i0 + 3;
      for (;;) {
        bool ok = true;
        if (i0 != 0) ok = ok && (alu(&bar[i0 * 32]) >= target);
        ok = ok && (alu(&bar[i1 * 32]) >= target);
        ok = ok && (alu(&bar[i2 * 32]) >= target);
        ok = ok && (alu(&bar[i3 * 32]) >= target);
        if (__all(ok)) break;
        __builtin_amdgcn_s_sleep(1);
      }
      if (tid < 8) asu(&bar[(256 + tid) * 32], target);
    }
  } else {
    if (tid == 0) {
      asm volatile("s_waitcnt vmcnt(0)" ::: "memory");
      asu(&bar[bk * 32], target);
      unsigned* wk = &bar[(256 + (bk & 7)) * 32];
      while (alu(wk) < target) __builtin_amdgcn_s_sleep(1);
    }
  }
  __syncthreads();
}

// ---- one wave's LSTM share: one k-slice (8-way split), both m-halves ----
// Byte-identical math to R6; panel k-tiles are disjoint across waves.
template<int LS, int W>
__device__ __forceinline__ void lstm_wave(
    const ushortt* __restrict__ s0, const ushortt* __restrict__ s2,
    const float* __restrict__ numq, const float* __restrict__ invden,
    const short* __restrict__ pan,
    int l, ushortt* xs, fvec4& z0, fvec4& z1)
{
  constexpr int NC  = LS ? 5 : (W < 4 ? 4 : 3);                 // 64-col chunks
  constexpr int CB  = LS ? W * 320 : (W < 4 ? W * 256 : 1024 + (W - 4) * 192);
  constexpr int KT0 = CB / 32;
  constexpr int BD0 = LS ? 1024 : 256;          // end of s0 segment
  constexpr int BD1 = LS ? 1536 : 768;          // end of actx segment
  const int u8 = l & 15, rj = l >> 4;           // load mapping
  const int m = l & 15, kg = l >> 4;            // frag mapping

  #pragma unroll
  for (int c = 0; c < NC; ++c) {
    const int c0 = CB + c * 64;                  // compile-time
    u64 L[8];
    if (c0 >= BD0 && c0 < BD1) {                 // actx segment: f32 num, scale
      const float* base = numq + (c0 - BD0) + u8 * 4;
      #pragma unroll
      for (int j = 0; j < 8; ++j) {
        int row = 4 * j + rj;
        const float* fp = base + (size_t)row * kEmb;
        U64u a, b2; a.u = ald64(fp); b2.u = ald64(fp + 2);
        float s = invden[row];
        U64u pk;
        pk.s[0] = bf16rn(a.f2.x * s);  pk.s[1] = bf16rn(a.f2.y * s);
        pk.s[2] = bf16rn(b2.f2.x * s); pk.s[3] = bf16rn(b2.f2.y * s);
        L[j] = pk.u;
      }
    } else {
      const ushortt* bsrc; int stride; bool coh;
      if (c0 < BD0) { bsrc = s0 + c0;       stride = (LS ? 1024 : 256); coh = (LS == 1); }
      else          { bsrc = s2 + c0 - BD1; stride = 1024;              coh = true; }
      #pragma unroll
      for (int j = 0; j < 8; ++j) {
        const ushortt* ap = bsrc + (size_t)(4 * j + rj) * stride + u8 * 4;
        L[j] = coh ? ald64(ap) : *reinterpret_cast<const u64*>(ap);
      }
    }
    bh8_t f0 = *reinterpret_cast<const bh8_t*>(pan + (size_t)(KT0 + c * 2) * 512 + l * 8);
    bh8_t f1 = *reinterpret_cast<const bh8_t*>(pan + (size_t)(KT0 + c * 2 + 1) * 512 + l * 8);
    #pragma unroll
    for (int j = 0; j < 8; ++j) {
      int row = 4 * j + rj;
      int sw = u8 ^ ((row & 7) << 1);
      *reinterpret_cast<u64*>(xs + row * 64 + sw * 4) = L[j];
    }
    #pragma unroll
    for (int kt = 0; kt < 2; ++kt) {
      int sw = (2 * (kt * 4 + kg)) ^ ((m & 7) << 1);
      bh8_t a0 = *reinterpret_cast<const bh8_t*>(xs + m * 64 + sw * 4);
      bh8_t a1 = *reinterpret_cast<const bh8_t*>(xs + (16 + m) * 64 + sw * 4);
      bh8_t f = kt ? f1 : f0;
      z0 = __builtin_amdgcn_mfma_f32_16x16x32_bf16(a0, f, z0, 0, 0, 0);
      z1 = __builtin_amdgcn_mfma_f32_16x16x32_bf16(a1, f, z1, 0, 0, 0);
    }
  }
}

extern "C" __global__ void __launch_bounds__(NTHR, 4)
decoder_kernel(const float* __restrict__ gmem, const float* __restrict__ dec,
               const unsigned char* __restrict__ mask,
               const float* __restrict__ pw1, const float* __restrict__ pw2,
               const float* __restrict__ awih, const float* __restrict__ awhh,
               const float* __restrict__ abih, const float* __restrict__ abhh,
               const float* __restrict__ qw, const float* __restrict__ mw,
               const float* __restrict__ cvw, const float* __restrict__ locw,
               const float* __restrict__ vw,
               const float* __restrict__ dwih, const float* __restrict__ dwhh,
               const float* __restrict__ dbih, const float* __restrict__ dbhh,
               const float* __restrict__ pjw, const float* __restrict__ pjb,
               const float* __restrict__ gw, const float* __restrict__ gb,
               float* __restrict__ out, float* __restrict__ ws, int useg)
{
  __shared__ SMem sm;
  __shared__ float s_invden[32];
  const int bk = blockIdx.x, tid = threadIdx.x;
  unsigned genv_f = 0, bcnt = 0;
  unsigned* bar = reinterpret_cast<unsigned*>(ws + OFF_BAR);
  unsigned* cntF = &bar[264 * 32];
  unsigned* genF = &bar[265 * 32];

  ushortt* PREBu = reinterpret_cast<ushortt*>(ws + OFF_PREB);
  ushortt* PROCMBu = reinterpret_cast<ushortt*>(ws + OFF_PROCMB);
  ushortt* QWTBu = reinterpret_cast<ushortt*>(ws + OFF_QWTB);
  float* LWT = ws + OFF_LWT;
  ushortt* AHBu = reinterpret_cast<ushortt*>(ws + OFF_AHB);
  ushortt* DHBu = reinterpret_cast<ushortt*>(ws + OFF_DHB);
  float* DH = ws + OFF_DH;
  float* AC = ws + OFF_AC;
  float* DC = ws + OFF_DC;
  float* ACTX = ws + OFF_ACTX;
  float* AWp = ws + OFF_AW;
  float* AWC = ws + OFF_AWC;
  float* PAW = ws + OFF_PAW;
  float* NUM = ws + OFF_NUM;
  float* DEN = ws + OFF_DEN;
  short* PANS = reinterpret_cast<short*>(ws + OFF_PAN);
  ushortt* GMB = reinterpret_cast<ushortt*>(ws + OFF_GMB);

  // ---------------- P0: zero state + QWTB + LWT ----------------
  for (int i = bk * NTHR + tid; i < STATE_SZ; i += NBLK * NTHR) (ws + OFF_STATE)[i] = 0.f;
  for (int i = bk * NTHR + tid; i < kAdim * kArnn; i += NBLK * NTHR)
    QWTBu[i] = bf16rn(qw[i]);
  for (int i = bk * NTHR + tid; i < kAdim * kNF; i += NBLK * NTHR) {
    int d = i >> 5, f = i & 31;
    LWT[d * 33 + f] = locw[i];
  }
  gbar_full(cntF, genF, genv_f);

  // ---------------- P1: den init, proc_mem (+bf16 gmem copy), prenet, panels ----------------
  if (bk == 0 && tid < 2 * kB) asf(&DEN[tid], 1.0f);
  for (int it = 0; it < 16; ++it) {
    int task0 = bk * 64 + it * 4;
    for (int i = tid; i < 2048; i += NTHR) {
      int pr = i >> 9, h = i & 511;
      sm.m.mem_s[pr][h] = gmem[(size_t)(task0 + pr) * kEmb + h];
    }
    __syncthreads();
    if (tid < 512) {
      int pr = tid >> 7, d = tid & 127;
      const float* mwr = mw + d * kEmb;
      float acc = 0.f;
      for (int h = 0; h < kEmb; ++h) acc = fmaf(sm.m.mem_s[pr][h], mwr[h], acc);
      PROCMBu[(size_t)(task0 + pr) * kAdim + d] = bf16rn(acc);
    }
    if (useg) {
      for (int i = tid; i < 2048; i += NTHR) {
        int pr = i >> 9, h = i & 511;
        GMB[(size_t)(task0 + pr) * kEmb + h] = bf16rn(sm.m.mem_s[pr][h]);
      }
    }
    __syncthreads();
  }
  for (int g = bk; g < 2000; g += NBLK) {
    int t_idx = g >> 2;
    int b0 = (g & 3) * 8;
    if (t_idx == 0) {
      for (int i = tid; i < 8 * kPre; i += NTHR)
        PREBu[(size_t)(b0 + (i >> 8)) * kPre + (i & 255)] = 0;
      continue;
    }
    for (int i = tid; i < 640; i += NTHR) {
      int bb = i / 80, m2 = i % 80;
      sm.p.x8[bb][m2] = dec[((size_t)(b0 + bb) * kNMel + m2) * kT + (t_idx - 1)];
    }
    __syncthreads();
    if (tid < 512) {
      int u = tid & 255, rep = tid >> 8;
      float acc[4] = {0.f, 0.f, 0.f, 0.f};
      for (int m2 = 0; m2 < 80; ++m2) {
        float w = pw1[u * kNMel + m2];
        #pragma unroll
        for (int r = 0; r < 4; ++r) acc[r] = fmaf(w, sm.p.x8[rep * 4 + r][m2], acc[r]);
      }
      #pragma unroll
      for (int r = 0; r < 4; ++r) sm.p.h1[rep * 4 + r][u] = fmaxf(acc[r], 0.f);
    }
    __syncthreads();
    if (tid < 512) {
      int u = tid & 255, rep = tid >> 8;
      float acc[4] = {0.f, 0.f, 0.f, 0.f};
      for (int k = 0; k < kPre; ++k) {
        float w = pw2[u * kPre + k];
        #pragma unroll
        for (int r = 0; r < 4; ++r) acc[r] = fmaf(w, sm.p.h1[rep * 4 + r][k], acc[r]);
      }
      #pragma unroll
      for (int r = 0; r < 4; ++r)
        PREBu[((size_t)t_idx * kB + b0 + rep * 4 + r) * kPre + u] = bf16rn(fmaxf(acc[r], 0.f));
    }
    __syncthreads();
  }
  {  // pack per-block bf16 weight panels in MFMA B-fragment order
    const int UNITS = NBLK * KT_ALL * 64;
    for (int u = bk * NTHR + tid; u < UNITS; u += NBLK * NTHR) {
      int bkk = u / (KT_ALL * 64);
      int rem = u - bkk * (KT_ALL * 64);
      int kta = rem >> 6, l = rem & 63;
      int lstm = (kta >= KT_A);
      int kt = lstm ? kta - KT_A : kta;
      int n = l & 15, kg = l >> 4;
      int r = (n >> 2) * 1024 + bkk * 4 + (n & 3);
      bh8_t v;
      #pragma unroll
      for (int j = 0; j < 8; ++j) {
        int k = kt * 32 + kg * 8 + j;
        float wv;
        if (!lstm) wv = (k < 768) ? awih[(size_t)r * 768 + k] : awhh[(size_t)r * 1024 + (k - 768)];
        else       wv = (k < 1536) ? dwih[(size_t)r * 1536 + k] : dwhh[(size_t)r * 1024 + (k - 1536)];
        v[j] = (short)bf16rn(wv);
      }
      *reinterpret_cast<bh8_t*>(PANS + (size_t)u * 8) = v;
    }
  }
  gbar_full(cntF, genF, genv_f);

  // ---------------- main scan: 2 barriers/step ----------------
  for (int t = 0; t <= kT; ++t) {
    const int p = t & 1, q = p ^ 1;
    float* nump = NUM + p * kB * kEmb;
    const float* numq = NUM + q * kB * kEmb;

    // ---- phase X: finalize(t-1) + aLSTM(t) + dLSTM(t-1), 16 waves / 8-way k-split ----
    if (tid < kB) s_invden[tid] = 1.0f / alf(DEN + q * kB + tid);
    __syncthreads();
    if (t > 0 && tid < 64) {   // finalize step t-1 attention (own 64 elements)
      int idx = bk * 64 + tid;
      int b2 = idx >> 9;
      float invd = s_invden[b2];
      float av = PAW[idx] * invd;          // PAW block-private (plain)
      asf(&AWp[idx], av);
      asf(&AWC[idx], alf(&AWC[idx]) + av);
      asf(&ACTX[idx], alf(&numq[idx]) * invd);
    }
    if (t < kT) {
      if (tid < 64) asf(&nump[bk * 64 + tid], 0.f);
      if (bk == 0 && tid < kB) asf(DEN + p * kB + tid, 0.f);
    }
    {
      const int wid = tid >> 6, l = tid & 63;
      fvec4 z0 = {0.f, 0.f, 0.f, 0.f}, z1 = z0;
      const ushortt* AHBq_ = AHBu + q * kB * kArnn;
      const ushortt* DHBp_ = DHBu + p * kB * kArnn;
      const ushortt* preb_t = PREBu + (size_t)t * kB * kPre;
      ushortt* xs = &sm.x1.xs[wid][0];
      const short* panb = PANS + (size_t)bk * (KT_ALL * 512);
      const short* pand = panb + KT_A * 512;
      if (wid < 8) {
        if (t < kT) {
          switch (wid) {
            case 0: lstm_wave<0,0>(preb_t, AHBq_, numq, s_invden, panb, l, xs, z0, z1); break;
            case 1: lstm_wave<0,1>(preb_t, AHBq_, numq, s_invden, panb, l, xs, z0, z1); break;
            case 2: lstm_wave<0,2>(preb_t, AHBq_, numq, s_invden, panb, l, xs, z0, z1); break;
            case 3: lstm_wave<0,3>(preb_t, AHBq_, numq, s_invden, panb, l, xs, z0, z1); break;
            case 4: lstm_wave<0,4>(preb_t, AHBq_, numq, s_invden, panb, l, xs, z0, z1); break;
            case 5: lstm_wave<0,5>(preb_t, AHBq_, numq, s_invden, panb, l, xs, z0, z1); break;
            case 6: lstm_wave<0,6>(preb_t, AHBq_, numq, s_invden, panb, l, xs, z0, z1); break;
            default: lstm_wave<0,7>(preb_t, AHBq_, numq, s_invden, panb, l, xs, z0, z1); break;
          }
        }
      } else {
        if (t > 0) {
          switch (wid) {
            case 8:  lstm_wave<1,0>(AHBq_, DHBp_, numq, s_invden, pand, l, xs, z0, z1); break;
            case 9:  lstm_wave<1,1>(AHBq_, DHBp_, numq, s_invden, pand, l, xs, z0, z1); break;
            case 10: lstm_wave<1,2>(AHBq_, DHBp_, numq, s_invden, pand, l, xs, z0, z1); break;
            case 11: lstm_wave<1,3>(AHBq_, DHBp_, numq, s_invden, pand, l, xs, z0, z1); break;
            case 12: lstm_wave<1,4>(AHBq_, DHBp_, numq, s_invden, pand, l, xs, z0, z1); break;
            case 13: lstm_wave<1,5>(AHBq_, DHBp_, numq, s_invden, pand, l, xs, z0, z1); break;
            case 14: lstm_wave<1,6>(AHBq_, DHBp_, numq, s_invden, pand, l, xs, z0, z1); break;
            default: lstm_wave<1,7>(AHBq_, DHBp_, numq, s_invden, pand, l, xs, z0, z1); break;
          }
        }
      }
      __syncthreads();   // staging LDS dead; overlay with zred
      if (wid < 8) {
        *reinterpret_cast<fvec4*>(&sm.x2.zra[wid][0][l][0]) = z0;
        *reinterpret_cast<fvec4*>(&sm.x2.zra[wid][1][l][0]) = z1;
      } else {
        *reinterpret_cast<fvec4*>(&sm.x2.zrd[wid - 8][0][l][0]) = z0;
        *reinterpret_cast<fvec4*>(&sm.x2.zrd[wid - 8][1][l][0]) = z1;
      }
    }
    __syncthreads();
    if (tid < 256) {  // gate epilogue (8-way slice reduce)
      const int ls = tid >> 7, uu = (tid >> 5) & 3, b = tid & 31;
      const bool go = (ls == 0) ? (t < kT) : (t > 0);
      if (go) {
        const int mt = b >> 4, mm = b & 15;
        const int lane_base = (mm >> 2) * 16, rr = mm & 3;
        float zg[4];
        #pragma unroll
        for (int g = 0; g < 4; ++g) {
          int ln = lane_base + g * 4 + uu;
          float s = 0.f;
          if (ls == 0) {
            #pragma unroll
            for (int w = 0; w < 8; ++w) s += sm.x2.zra[w][mt][ln][rr];
          } else {
            #pragma unroll
            for (int w = 0; w < 8; ++w) s += sm.x2.zrd[w][mt][ln][rr];
          }
          int rg = g * 1024 + bk * 4 + uu;
          s += (ls ? dbih[rg] + dbhh[rg] : abih[rg] + abhh[rg]);
          zg[g] = s;
        }
        float* cst = ls ? DC : AC;
        const int idx = b * kArnn + bk * 4 + uu;
        float c = sigf(zg[1]) * cst[idx] + sigf(zg[0]) * tanhfast(zg[2]);
        cst[idx] = c;
        float h = sigf(zg[3]) * tanhfast(c);
        if (ls) asf(&DH[q * kB * kArnn + idx], h);
        sm.x2.hb[ls][b][uu] = h;
      }
    }
    __syncthreads();
    if (tid < 64) {  // pack h -> bf16 state
      int ls = tid >> 5, b = tid & 31;
      bool go2 = ls ? (t > 0) : (t < kT);
      if (go2) {
        U64u pk;
        #pragma unroll
        for (int j = 0; j < 4; ++j) pk.s[j] = bf16rn(sm.x2.hb[ls][b][j]);
        ushortt* dst = (ls ? (DHBu + q * kB * kArnn) : (AHBu + p * kB * kArnn)) + b * kArnn + bk * 4;
        as64(dst, pk.u);
      }
    }
    gbar_light(bar, ++bcnt, bk, tid);

    if (t < kT) {
      // ---- phase B: attention step t (+ mel/gate of t-1) ----
      const int b = bk >> 3, sub = bk & 7, j0 = sub * 64;
      const int pbase = (sub == 0) ? 0 : 21 + (sub - 1) * 20;
      const int pcnt = (sub == 0) ? 21 : 20;
      const ushortt* AHBp_ = AHBu + p * kB * kArnn;
      // S1: staging
      if (tid < 256) {
        U64u v; v.u = ald64(AHBp_ + b * kArnn + tid * 4);
        #pragma unroll
        for (int j = 0; j < 4; ++j) sm.b.ahb_s[tid * 4 + j] = bf2f(v.s[j]);
      }
      for (int i = tid; i < 94; i += NTHR) {
        int jj = j0 - kPad + i;
        bool ok = (jj >= 0 && jj < kNctx);
        sm.b.aw_s[i] = ok ? alf(&AWp[b * kNctx + jj]) : 0.f;
        sm.b.awc_s[i] = ok ? alf(&AWC[b * kNctx + jj]) : 0.f;
      }
      for (int i = tid; i < kNF * 2 * kKS; i += NTHR) sm.b.cw[i] = cvw[i];
      for (int i = tid; i < kAdim * 33; i += NTHR) sm.b.lwt[i] = LWT[i];
      for (int i = tid; i < kAdim; i += NTHR) sm.b.vw_s[i] = vw[i];
      {  // proc_mem tile (bf16)
        const fvec4* src = reinterpret_cast<const fvec4*>(PROCMBu + (size_t)(b * kNctx + j0) * kAdim);
        fvec4* dst = reinterpret_cast<fvec4*>(sm.b.pm);
        for (int i = tid; i < 1024; i += NTHR) dst[i] = src[i];
      }
      if (sub < 4 && t > 0) {
        for (int i = tid; i < kArnn + kEmb; i += NTHR)
          sm.b.dhc[i] = (i < kArnn) ? alf(&DH[q * kB * kArnn + b * kArnn + i])
                                    : alf(&ACTX[b * kEmb + (i - kArnn)]);
      }
      __syncthreads();
      // S2: q partial (8-way K split, contiguous bf16 weights)
      {
        int d = tid & 127, qr = tid >> 7;   // 0..7
        const ushortt* wq = QWTBu + (size_t)d * kArnn + qr * 128;
        const float* ahs = sm.b.ahb_s + qr * 128;
        float acc = 0.f;
        #pragma unroll 4
        for (int h8 = 0; h8 < 16; ++h8) {
          U64u a, c2;
          a.u = *reinterpret_cast<const u64*>(wq + h8 * 8);
          c2.u = *reinterpret_cast<const u64*>(wq + h8 * 8 + 4);
          #pragma unroll
          for (int j = 0; j < 4; ++j) acc = fmaf(bf2f(a.s[j]), ahs[h8 * 8 + j], acc);
          #pragma unroll
          for (int j = 0; j < 4; ++j) acc = fmaf(bf2f(c2.s[j]), ahs[h8 * 8 + 4 + j], acc);
        }
        sm.b.psum[tid] = acc;
      }
      __syncthreads();
      // S3: q reduce + conv + projection partials
      if (tid < kAdim) {
        float s = 0.f;
        #pragma unroll
        for (int k = 0; k < 8; ++k) s += sm.b.psum[tid + 128 * k];
        sm.b.q_s[tid] = s;
      }
      if (tid < 512) {
        int j = tid >> 3, f0 = (tid & 7) * 4;
        #pragma unroll
        for (int fi = 0; fi < 4; ++fi) {
          int f = f0 + fi;
          const float* w0 = &sm.b.cw[f * 62];
          float s = 0.f;
          for (int k = 0; k < kKS; ++k)
            s = fmaf(sm.b.aw_s[j + k], w0[k], fmaf(sm.b.awc_s[j + k], w0[31 + k], s));
          sm.b.loc_s[j * 33 + f] = s;
        }
      }
      if (sub < 4 && t > 0 && tid < pcnt * 6) {
        int ol = tid / 6, kc = tid % 6, og = pbase + ol;
        const float* row = (og < kNMel) ? pjw + (size_t)og * (kArnn + kEmb) : gw;
        const float* x = sm.b.dhc + kc * 256;
        const float* r2 = row + kc * 256;
        float acc = 0.f;
        for (int k = 0; k < 256; ++k) acc = fmaf(r2[k], x[k], acc);
        sm.b.pprj[tid] = acc;
      }
      __syncthreads();
      // S4: energies + exp; projection finals
      if (tid < 512) {
        int j = tid >> 3, grp = tid & 7, jj = j0 + j;
        float pe = 0.f;
        #pragma unroll 4
        for (int dd = 0; dd < 16; ++dd) {
          int d = grp + 8 * dd;
          float l2 = 0.f;
          const float* ls2 = &sm.b.loc_s[j * 33];
          const float* lw2 = &sm.b.lwt[d * 33];
          #pragma unroll 8
          for (int f = 0; f < kNF; ++f) l2 = fmaf(ls2[f], lw2[f], l2);
          float x = sm.b.q_s[d] + bf2f(sm.b.pm[j * kAdim + d]) + l2;
          pe = fmaf(sm.b.vw_s[d], tanhfast(x), pe);
        }
        pe += __shfl_xor(pe, 1);
        pe += __shfl_xor(pe, 2);
        pe += __shfl_xor(pe, 4);
        if (grp == 0) {
          float pv = mask[b * kNctx + jj] ? 0.f : __expf(pe);
          sm.b.p_s[j] = pv;
          PAW[b * kNctx + jj] = pv;   // block-private
        }
      }
      if (sub < 4 && t > 0 && tid < pcnt) {
        int og = pbase + tid;
        float val = (og < kNMel) ? pjb[og] : gb[0];
        #pragma unroll
        for (int kc = 0; kc < 6; ++kc) val += sm.b.pprj[tid * 6 + kc];
        if (og < kNMel) out[((size_t)b * kNMel + og) * kT + (t - 1)] = val;
        else out[(size_t)kB * kNMel * kT + b * kT + (t - 1)] = val;
      }
      __syncthreads();
      // S5: denominator + numerator (parity-p buffers; j-range split 2-way)
      if (tid < 64) {
        float v = sm.b.p_s[tid];
        #pragma unroll
        for (int o = 1; o < 64; o <<= 1) v += __shfl_xor(v, o);
        if (tid == 0) atomicAdd(DEN + p * kB + b, v);
      }
      {
        int col = tid & 511, half = tid >> 9;
        int jbase = half * 32;
        if (useg) {
          const ushortt* memb = GMB + (size_t)(b * kNctx + j0 + jbase) * kEmb + col;
          float a0 = 0.f, a1 = 0.f, a2 = 0.f, a3 = 0.f;
          #pragma unroll 4
          for (int jj2 = 0; jj2 < 32; jj2 += 4) {
            a0 = fmaf(sm.b.p_s[jbase + jj2],     bf2f(memb[(size_t)jj2 * kEmb]), a0);
            a1 = fmaf(sm.b.p_s[jbase + jj2 + 1], bf2f(memb[(size_t)(jj2 + 1) * kEmb]), a1);
            a2 = fmaf(sm.b.p_s[jbase + jj2 + 2], bf2f(memb[(size_t)(jj2 + 2) * kEmb]), a2);
            a3 = fmaf(sm.b.p_s[jbase + jj2 + 3], bf2f(memb[(size_t)(jj2 + 3) * kEmb]), a3);
          }
          atomicAdd(&nump[b * kEmb + col], (a0 + a1) + (a2 + a3));
        } else {
          const float* memb = gmem + (size_t)(b * kNctx + j0 + jbase) * kEmb + col;
          float a0 = 0.f, a1 = 0.f;
          #pragma unroll 8
          for (int jj2 = 0; jj2 < 32; jj2 += 2) {
            a0 = fmaf(sm.b.p_s[jbase + jj2], memb[(size_t)jj2 * kEmb], a0);
            a1 = fmaf(sm.b.p_s[jbase + jj2 + 1], memb[(size_t)(jj2 + 1) * kEmb], a1);
          }
          atomicAdd(&nump[b * kEmb + col], a0 + a1);
        }
      }
      gbar_light(bar, ++bcnt, bk, tid);
    }
  }

  // final projection t=499 (dh parity 1; ACTX(499) finalized in phase X(500))
  if (bk < kB) {
    const int b = bk;
    for (int i = tid; i < kArnn + kEmb; i += NTHR)
      sm.b.dhc[i] = (i < kArnn) ? alf(&DH[1 * kB * kArnn + b * kArnn + i])
                                : alf(&ACTX[b * kEmb + (i - kArnn)]);
    __syncthreads();
    if (tid < 486) {
      int ol = tid / 6, kc = tid % 6;
      const float* row = (ol < kNMel) ? pjw + (size_t)ol * (kArnn + kEmb) : gw;
      const float* x = sm.b.dhc + kc * 256;
      const float* r2 = row + kc * 256;
      float acc = 0.f;
      for (int k = 0; k < 256; ++k) acc = fmaf(r2[k], x[k], acc);
      sm.b.psum[tid] = acc;
    }
    __syncthreads();
    if (tid < 81) {
      float val = (tid < kNMel) ? pjb[tid] : gb[0];
      #pragma unroll
      for (int kc = 0; kc < 6; ++kc) val += sm.b.psum[tid * 6 + kc];
      if (tid < kNMel) out[((size_t)b * kNMel + tid) * kT + (kT - 1)] = val;
      else out[(size_t)kB * kNMel * kT + b * kT + (kT - 1)] = val;
    }
  }
}

extern "C" void kernel_launch(void* const* d_in, const int* in_sizes, int n_in,
                              void* d_out, int out_size, void* d_ws, size_t ws_size,
                              hipStream_t stream) {
  const float* gmem = (const float*)d_in[0];
  const float* dec = (const float*)d_in[1];
  const unsigned char* mask = (const unsigned char*)d_in[2];
  const float* pw1 = (const float*)d_in[3];
  const float* pw2 = (const float*)d_in[4];
  const float* awih = (const float*)d_in[5];
  const float* awhh = (const float*)d_in[6];
  const float* abih = (const float*)d_in[7];
  const float* abhh = (const float*)d_in[8];
  const float* qw = (const float*)d_in[9];
  const float* mw = (const float*)d_in[10];
  const float* cvw = (const float*)d_in[11];
  const float* locw = (const float*)d_in[12];
  const float* vw = (const float*)d_in[13];
  const float* dwih = (const float*)d_in[14];
  const float* dwhh = (const float*)d_in[15];
  const float* dbih = (const float*)d_in[16];
  const float* dbhh = (const float*)d_in[17];
  const float* pjw = (const float*)d_in[18];
  const float* pjb = (const float*)d_in[19];
  const float* gw = (const float*)d_in[20];
  const float* gb = (const float*)d_in[21];
  float* out = (float*)d_out;
  float* ws = (float*)d_ws;

  int useg = (ws_size >= (size_t)(OFF_GMB + GMB_SZ) * sizeof(float)) ? 1 : 0;

  // entire barrier region (flags + wake lines + init barrier) must start at 0
  hipMemsetAsync((char*)d_ws + (size_t)OFF_BAR * sizeof(float), 0,
                 (size_t)BAR_LINES * 128, stream);
  hipLaunchKernelGGL(decoder_kernel, dim3(NBLK), dim3(NTHR), 0, stream,
                     gmem, dec, mask, pw1, pw2, awih, awhh, abih, abhh, qw, mw,
                     cvw, locw, vw, dwih, dwhh, dbih, dbhh, pjw, pjb, gw, gb,
                     out, ws, useg);
}

// Round 13
// 42563.599 us; speedup vs baseline: 1.0167x; 1.0167x over previous
//
#include <hip/hip_runtime.h>

#define NBLK 256
#define NTHR 1024

constexpr int kNMel = 80, kArnn = 1024, kAdim = 128, kEmb = 512, kPre = 256;
constexpr int kNF = 32, kKS = 31, kB = 32, kNctx = 512, kT = 500, kPad = 15;

constexpr int KT_A = 56;   // 1792/32 k-tiles (aLSTM: 256 prenet + 512 actx + 1024 ah)
constexpr int KT_D = 80;   // 2560/32 k-tiles (dLSTM: 1024 ah + 512 actx + 1024 dh)
constexpr int KT_ALL = KT_A + KT_D;

// ---- workspace layout (float offsets) ----
constexpr int OFF_PREB   = 0;                                    // bf16 [500][32][256]
constexpr int OFF_PROCMB = OFF_PREB + kT * kB * kPre / 2;        // bf16 [32*512][128]
constexpr int OFF_QWTB   = OFF_PROCMB + kB * kNctx * kAdim / 2;  // bf16 [128][1024]
constexpr int OFF_LWT    = OFF_QWTB + kAdim * kArnn / 2;         // f32 [128*33]
constexpr int OFF_STATE  = OFF_LWT + kAdim * 33;
constexpr int OFF_AHB    = OFF_STATE;                            // bf16 [2][32][1024]
constexpr int OFF_DHB    = OFF_AHB + 2 * kB * kArnn / 2;         // bf16 [2][32][1024]
constexpr int OFF_DH     = OFF_DHB + 2 * kB * kArnn / 2;         // f32 [2][32][1024]
constexpr int OFF_AC     = OFF_DH + 2 * kB * kArnn;              // f32 [32][1024]
constexpr int OFF_DC     = OFF_AC + kB * kArnn;
constexpr int OFF_ACTX   = OFF_DC + kB * kArnn;                  // f32 [32][512]
constexpr int OFF_AW     = OFF_ACTX + kB * kEmb;                 // f32 [32][512]
constexpr int OFF_AWC    = OFF_AW + kB * kNctx;
constexpr int OFF_PAW    = OFF_AWC + kB * kNctx;                 // block-private
constexpr int OFF_NUM    = OFF_PAW + kB * kNctx;                 // f32 [2][32][512]
constexpr int OFF_DEN    = OFF_NUM + 2 * kB * kEmb;              // f32 [2][32]
constexpr int OFF_END    = OFF_DEN + 2 * kB;
constexpr int STATE_SZ   = OFF_END - OFF_STATE;
// barrier region: one 128B line per word (per-block flags, wake replicas, init)
constexpr int OFF_BAR    = OFF_END;
constexpr int BAR_LINES  = 266;
constexpr int OFF_PAN    = OFF_BAR + BAR_LINES * 32;             // bf16 panels
constexpr int PAN_SZ     = NBLK * KT_ALL * 256;                  // floats

typedef __attribute__((ext_vector_type(4))) float fvec4;
typedef __attribute__((ext_vector_type(8))) short bh8_t;
typedef unsigned long long u64;
typedef unsigned short ushortt;

union U64u { u64 u; float2 f2; ushortt s[4]; };

// LDS: persistent per-block tiles + phase-overlaid union (total ~144 KB)
struct SMemS {
  ushortt gmb[64 * kEmb];      // 64 KB: memory[b, j0..j0+63, :] bf16 (persistent)
  ushortt pm[64 * kAdim];      // 16 KB: proc_mem tile bf16 (persistent)
  union {
    struct { ushortt xs[16][2048]; } x1;                             // 64 KB staging
    struct { float zra[8][2][64][4]; float zrd[8][2][64][4];
             float hb[2][32][4]; } x2;                               // 33 KB overlay
    struct { float ahb_s[kArnn]; float vw_s[kAdim]; float psum[1024]; float q_s[kAdim];
             float aw_s[96]; float awc_s[96]; float cw[kNF * 2 * kKS];
             float loc_s[64 * 33]; float p_s[64]; float lwt[kAdim * 33];
             float dhc[kArnn + kEmb]; float pprj[126]; } b;          // ~50 KB
    struct { float x8[8][80]; float h1[8][256]; } p;
    struct { float mem_s[4][512]; } m;
  } u;
};

__device__ __forceinline__ float sigf(float x) { return 1.0f / (1.0f + __expf(-x)); }
__device__ __forceinline__ float tanhfast(float x) { return 1.0f - 2.0f / (__expf(2.0f * x) + 1.0f); }

__device__ __forceinline__ ushortt bf16rn(float f) {
  unsigned u = __float_as_uint(f);
  unsigned r = (u + 0x7FFFu + ((u >> 16) & 1u)) >> 16;
  return (ushortt)r;
}
__device__ __forceinline__ float bf2f(ushortt v) {
  return __uint_as_float((unsigned)v << 16);
}

// relaxed agent-scope atomics: cross-XCD coherent, no cache-invalidation side effects
__device__ __forceinline__ u64 ald64(const void* p) {
  return __hip_atomic_load((const u64*)p, __ATOMIC_RELAXED, __HIP_MEMORY_SCOPE_AGENT);
}
__device__ __forceinline__ float alf(const float* p) {
  return __hip_atomic_load(p, __ATOMIC_RELAXED, __HIP_MEMORY_SCOPE_AGENT);
}
__device__ __forceinline__ void asf(float* p, float v) {
  __hip_atomic_store(p, v, __ATOMIC_RELAXED, __HIP_MEMORY_SCOPE_AGENT);
}
__device__ __forceinline__ void as64(void* p, u64 v) {
  __hip_atomic_store((u64*)p, v, __ATOMIC_RELAXED, __HIP_MEMORY_SCOPE_AGENT);
}
__device__ __forceinline__ unsigned alu(const unsigned* p) {
  return __hip_atomic_load(p, __ATOMIC_RELAXED, __HIP_MEMORY_SCOPE_AGENT);
}
__device__ __forceinline__ void asu(unsigned* p, unsigned v) {
  __hip_atomic_store(p, v, __ATOMIC_RELAXED, __HIP_MEMORY_SCOPE_AGENT);
}

// heavyweight init barrier (acq/rel) — used twice, before the scan
__device__ __forceinline__ void gbar_full(unsigned* cnt, unsigned* gen, unsigned& genv) {
  __syncthreads();
  if (threadIdx.x == 0) {
    __threadfence();
    unsigned arrived = __hip_atomic_fetch_add(cnt, 1u, __ATOMIC_ACQ_REL, __HIP_MEMORY_SCOPE_AGENT) + 1u;
    if (arrived == (unsigned)NBLK) {
      __hip_atomic_store(cnt, 0u, __ATOMIC_RELAXED, __HIP_MEMORY_SCOPE_AGENT);
      __hip_atomic_fetch_add(gen, 1u, __ATOMIC_ACQ_REL, __HIP_MEMORY_SCOPE_AGENT);
    } else {
      while (__hip_atomic_load(gen, __ATOMIC_ACQUIRE, __HIP_MEMORY_SCOPE_AGENT) == genv) {
        __builtin_amdgcn_s_sleep(2);
      }
    }
    ++genv;
  }
  __syncthreads();
}

// lightweight scan barrier: per-block flag lines; block 0 sweeps, fans out wake gen
__device__ __forceinline__ void gbar_light(unsigned* bar, unsigned target, int bk, int tid) {
  asm volatile("s_waitcnt vmcnt(0) lgkmcnt(0)" ::: "memory");
  __syncthreads();
  if (bk == 0) {
    if (tid < 64) {
      if (tid == 0) asm volatile("s_waitcnt vmcnt(0)" ::: "memory");
      unsigned i0 = (unsigned)tid * 4, i1 = i0 + 1, i2 = i0 + 2, i3 = i0 + 3;
      for (;;) {
        bool ok = true;
        if (i0 != 0) ok = ok && (alu(&bar[i0 * 32]) >= target);
        ok = ok && (alu(&bar[i1 * 32]) >= target);
        ok = ok && (alu(&bar[i2 * 32]) >= target);
        ok = ok && (alu(&bar[i3 * 32]) >= target);
        if (__all(ok)) break;
        __builtin_amdgcn_s_sleep(1);
      }
      if (tid < 8) asu(&bar[(256 + tid) * 32], target);
    }
  } else {
    if (tid == 0) {
      asm volatile("s_waitcnt vmcnt(0)" ::: "memory");
      asu(&bar[bk * 32], target);
      unsigned* wk = &bar[(256 + (bk & 7)) * 32];
      while (alu(wk) < target) __builtin_amdgcn_s_sleep(1);
    }
  }
  __syncthreads();
}

// ---- one wave's LSTM share: one k-slice (8-way split), both m-halves ----
template<int LS, int W>
__device__ __forceinline__ void lstm_wave(
    const ushortt* __restrict__ s0, const ushortt* __restrict__ s2,
    const float* __restrict__ numq, const float* __restrict__ invden,
    const short* __restrict__ pan,
    int l, ushortt* xs, fvec4& z0, fvec4& z1)
{
  constexpr int NC  = LS ? 5 : (W < 4 ? 4 : 3);                 // 64-col chunks
  constexpr int CB  = LS ? W * 320 : (W < 4 ? W * 256 : 1024 + (W - 4) * 192);
  constexpr int KT0 = CB / 32;
  constexpr int BD0 = LS ? 1024 : 256;          // end of s0 segment
  constexpr int BD1 = LS ? 1536 : 768;          // end of actx segment
  const int u8 = l & 15, rj = l >> 4;           // load mapping
  const int m = l & 15, kg = l >> 4;            // frag mapping

  #pragma unroll
  for (int c = 0; c < NC; ++c) {
    const int c0 = CB + c * 64;                  // compile-time
    u64 L[8];
    if (c0 >= BD0 && c0 < BD1) {                 // actx segment: f32 num, scale
      const float* base = numq + (c0 - BD0) + u8 * 4;
      #pragma unroll
      for (int j = 0; j < 8; ++j) {
        int row = 4 * j + rj;
        const float* fp = base + (size_t)row * kEmb;
        U64u a, b2; a.u = ald64(fp); b2.u = ald64(fp + 2);
        float s = invden[row];
        U64u pk;
        pk.s[0] = bf16rn(a.f2.x * s);  pk.s[1] = bf16rn(a.f2.y * s);
        pk.s[2] = bf16rn(b2.f2.x * s); pk.s[3] = bf16rn(b2.f2.y * s);
        L[j] = pk.u;
      }
    } else {
      const ushortt* bsrc; int stride; bool coh;
      if (c0 < BD0) { bsrc = s0 + c0;       stride = (LS ? 1024 : 256); coh = (LS == 1); }
      else          { bsrc = s2 + c0 - BD1; stride = 1024;              coh = true; }
      #pragma unroll
      for (int j = 0; j < 8; ++j) {
        const ushortt* ap = bsrc + (size_t)(4 * j + rj) * stride + u8 * 4;
        L[j] = coh ? ald64(ap) : *reinterpret_cast<const u64*>(ap);
      }
    }
    bh8_t f0 = *reinterpret_cast<const bh8_t*>(pan + (size_t)(KT0 + c * 2) * 512 + l * 8);
    bh8_t f1 = *reinterpret_cast<const bh8_t*>(pan + (size_t)(KT0 + c * 2 + 1) * 512 + l * 8);
    #pragma unroll
    for (int j = 0; j < 8; ++j) {
      int row = 4 * j + rj;
      int sw = u8 ^ ((row & 7) << 1);
      *reinterpret_cast<u64*>(xs + row * 64 + sw * 4) = L[j];
    }
    #pragma unroll
    for (int kt = 0; kt < 2; ++kt) {
      int sw = (2 * (kt * 4 + kg)) ^ ((m & 7) << 1);
      bh8_t a0 = *reinterpret_cast<const bh8_t*>(xs + m * 64 + sw * 4);
      bh8_t a1 = *reinterpret_cast<const bh8_t*>(xs + (16 + m) * 64 + sw * 4);
      bh8_t f = kt ? f1 : f0;
      z0 = __builtin_amdgcn_mfma_f32_16x16x32_bf16(a0, f, z0, 0, 0, 0);
      z1 = __builtin_amdgcn_mfma_f32_16x16x32_bf16(a1, f, z1, 0, 0, 0);
    }
  }
}

extern "C" __global__ void __launch_bounds__(NTHR, 4)
decoder_kernel(const float* __restrict__ gmem, const float* __restrict__ dec,
               const unsigned char* __restrict__ mask,
               const float* __restrict__ pw1, const float* __restrict__ pw2,
               const float* __restrict__ awih, const float* __restrict__ awhh,
               const float* __restrict__ abih, const float* __restrict__ abhh,
               const float* __restrict__ qw, const float* __restrict__ mw,
               const float* __restrict__ cvw, const float* __restrict__ locw,
               const float* __restrict__ vw,
               const float* __restrict__ dwih, const float* __restrict__ dwhh,
               const float* __restrict__ dbih, const float* __restrict__ dbhh,
               const float* __restrict__ pjw, const float* __restrict__ pjb,
               const float* __restrict__ gw, const float* __restrict__ gb,
               float* __restrict__ out, float* __restrict__ ws)
{
  __shared__ SMemS sm;
  __shared__ float s_invden[32];
  const int bk = blockIdx.x, tid = threadIdx.x;
  unsigned genv_f = 0, bcnt = 0;
  unsigned* bar = reinterpret_cast<unsigned*>(ws + OFF_BAR);
  unsigned* cntF = &bar[264 * 32];
  unsigned* genF = &bar[265 * 32];

  ushortt* PREBu = reinterpret_cast<ushortt*>(ws + OFF_PREB);
  ushortt* PROCMBu = reinterpret_cast<ushortt*>(ws + OFF_PROCMB);
  ushortt* QWTBu = reinterpret_cast<ushortt*>(ws + OFF_QWTB);
  float* LWT = ws + OFF_LWT;
  ushortt* AHBu = reinterpret_cast<ushortt*>(ws + OFF_AHB);
  ushortt* DHBu = reinterpret_cast<ushortt*>(ws + OFF_DHB);
  float* DH = ws + OFF_DH;
  float* AC = ws + OFF_AC;
  float* DC = ws + OFF_DC;
  float* ACTX = ws + OFF_ACTX;
  float* AWp = ws + OFF_AW;
  float* AWC = ws + OFF_AWC;
  float* PAW = ws + OFF_PAW;
  float* NUM = ws + OFF_NUM;
  float* DEN = ws + OFF_DEN;
  short* PANS = reinterpret_cast<short*>(ws + OFF_PAN);

  // ---------------- P0: zero state + QWTB + LWT ----------------
  for (int i = bk * NTHR + tid; i < STATE_SZ; i += NBLK * NTHR) (ws + OFF_STATE)[i] = 0.f;
  for (int i = bk * NTHR + tid; i < kAdim * kArnn; i += NBLK * NTHR)
    QWTBu[i] = bf16rn(qw[i]);
  for (int i = bk * NTHR + tid; i < kAdim * kNF; i += NBLK * NTHR) {
    int d = i >> 5, f = i & 31;
    LWT[d * 33 + f] = locw[i];
  }
  gbar_full(cntF, genF, genv_f);

  // ---------------- P1: den init, proc_mem, LDS tiles, prenet, panels ----------------
  if (bk == 0 && tid < 2 * kB) asf(&DEN[tid], 1.0f);
  for (int it = 0; it < 16; ++it) {
    int task0 = bk * 64 + it * 4;
    for (int i = tid; i < 2048; i += NTHR) {
      int pr = i >> 9, h = i & 511;
      sm.u.m.mem_s[pr][h] = gmem[(size_t)(task0 + pr) * kEmb + h];
    }
    __syncthreads();
    if (tid < 512) {
      int pr = tid >> 7, d = tid & 127;
      const float* mwr = mw + d * kEmb;
      float acc = 0.f;
      for (int h = 0; h < kEmb; ++h) acc = fmaf(sm.u.m.mem_s[pr][h], mwr[h], acc);
      PROCMBu[(size_t)(task0 + pr) * kAdim + d] = bf16rn(acc);
    }
    __syncthreads();
  }
  // persistent LDS tiles: this block's memory tile (rows bk*64..+63) + proc_mem tile
  for (int i = tid; i < 64 * kEmb; i += NTHR) {
    int j = i >> 9, h = i & 511;
    sm.gmb[i] = bf16rn(gmem[((size_t)bk * 64 + j) * kEmb + h]);
  }
  for (int i = tid; i < 64 * kAdim; i += NTHR)
    sm.pm[i] = PROCMBu[(size_t)bk * 64 * kAdim + i];
  __syncthreads();
  for (int g = bk; g < 2000; g += NBLK) {
    int t_idx = g >> 2;
    int b0 = (g & 3) * 8;
    if (t_idx == 0) {
      for (int i = tid; i < 8 * kPre; i += NTHR)
        PREBu[(size_t)(b0 + (i >> 8)) * kPre + (i & 255)] = 0;
      continue;
    }
    for (int i = tid; i < 640; i += NTHR) {
      int bb = i / 80, m2 = i % 80;
      sm.u.p.x8[bb][m2] = dec[((size_t)(b0 + bb) * kNMel + m2) * kT + (t_idx - 1)];
    }
    __syncthreads();
    if (tid < 512) {
      int u = tid & 255, rep = tid >> 8;
      float acc[4] = {0.f, 0.f, 0.f, 0.f};
      for (int m2 = 0; m2 < 80; ++m2) {
        float w = pw1[u * kNMel + m2];
        #pragma unroll
        for (int r = 0; r < 4; ++r) acc[r] = fmaf(w, sm.u.p.x8[rep * 4 + r][m2], acc[r]);
      }
      #pragma unroll
      for (int r = 0; r < 4; ++r) sm.u.p.h1[rep * 4 + r][u] = fmaxf(acc[r], 0.f);
    }
    __syncthreads();
    if (tid < 512) {
      int u = tid & 255, rep = tid >> 8;
      float acc[4] = {0.f, 0.f, 0.f, 0.f};
      for (int k = 0; k < kPre; ++k) {
        float w = pw2[u * kPre + k];
        #pragma unroll
        for (int r = 0; r < 4; ++r) acc[r] = fmaf(w, sm.u.p.h1[rep * 4 + r][k], acc[r]);
      }
      #pragma unroll
      for (int r = 0; r < 4; ++r)
        PREBu[((size_t)t_idx * kB + b0 + rep * 4 + r) * kPre + u] = bf16rn(fmaxf(acc[r], 0.f));
    }
    __syncthreads();
  }
  {  // pack per-block bf16 weight panels in MFMA B-fragment order
    const int UNITS = NBLK * KT_ALL * 64;
    for (int u = bk * NTHR + tid; u < UNITS; u += NBLK * NTHR) {
      int bkk = u / (KT_ALL * 64);
      int rem = u - bkk * (KT_ALL * 64);
      int kta = rem >> 6, l = rem & 63;
      int lstm = (kta >= KT_A);
      int kt = lstm ? kta - KT_A : kta;
      int n = l & 15, kg = l >> 4;
      int r = (n >> 2) * 1024 + bkk * 4 + (n & 3);
      bh8_t v;
      #pragma unroll
      for (int j = 0; j < 8; ++j) {
        int k = kt * 32 + kg * 8 + j;
        float wv;
        if (!lstm) wv = (k < 768) ? awih[(size_t)r * 768 + k] : awhh[(size_t)r * 1024 + (k - 768)];
        else       wv = (k < 1536) ? dwih[(size_t)r * 1536 + k] : dwhh[(size_t)r * 1024 + (k - 1536)];
        v[j] = (short)bf16rn(wv);
      }
      *reinterpret_cast<bh8_t*>(PANS + (size_t)u * 8) = v;
    }
  }
  gbar_full(cntF, genF, genv_f);

  // ---------------- main scan: 2 barriers/step ----------------
  for (int t = 0; t <= kT; ++t) {
    const int p = t & 1, q = p ^ 1;
    float* nump = NUM + p * kB * kEmb;
    const float* numq = NUM + q * kB * kEmb;

    // ---- phase X: finalize(t-1) + aLSTM(t) + dLSTM(t-1), 16 waves / 8-way k-split ----
    if (tid < kB) s_invden[tid] = 1.0f / alf(DEN + q * kB + tid);
    __syncthreads();
    if (t > 0 && tid < 64) {   // finalize step t-1 attention (own 64 elements)
      int idx = bk * 64 + tid;
      int b2 = idx >> 9;
      float invd = s_invden[b2];
      float av = PAW[idx] * invd;          // PAW block-private (plain)
      asf(&AWp[idx], av);
      asf(&AWC[idx], alf(&AWC[idx]) + av);
      asf(&ACTX[idx], alf(&numq[idx]) * invd);
    }
    if (t < kT) {
      if (tid < 64) asf(&nump[bk * 64 + tid], 0.f);
      if (bk == 0 && tid < kB) asf(DEN + p * kB + tid, 0.f);
    }
    {
      const int wid = tid >> 6, l = tid & 63;
      fvec4 z0 = {0.f, 0.f, 0.f, 0.f}, z1 = z0;
      const ushortt* AHBq_ = AHBu + q * kB * kArnn;
      const ushortt* DHBp_ = DHBu + p * kB * kArnn;
      const ushortt* preb_t = PREBu + (size_t)t * kB * kPre;
      ushortt* xs = &sm.u.x1.xs[wid][0];
      const short* panb = PANS + (size_t)bk * (KT_ALL * 512);
      const short* pand = panb + KT_A * 512;
      if (wid < 8) {
        if (t < kT) {
          switch (wid) {
            case 0: lstm_wave<0,0>(preb_t, AHBq_, numq, s_invden, panb, l, xs, z0, z1); break;
            case 1: lstm_wave<0,1>(preb_t, AHBq_, numq, s_invden, panb, l, xs, z0, z1); break;
            case 2: lstm_wave<0,2>(preb_t, AHBq_, numq, s_invden, panb, l, xs, z0, z1); break;
            case 3: lstm_wave<0,3>(preb_t, AHBq_, numq, s_invden, panb, l, xs, z0, z1); break;
            case 4: lstm_wave<0,4>(preb_t, AHBq_, numq, s_invden, panb, l, xs, z0, z1); break;
            case 5: lstm_wave<0,5>(preb_t, AHBq_, numq, s_invden, panb, l, xs, z0, z1); break;
            case 6: lstm_wave<0,6>(preb_t, AHBq_, numq, s_invden, panb, l, xs, z0, z1); break;
            default: lstm_wave<0,7>(preb_t, AHBq_, numq, s_invden, panb, l, xs, z0, z1); break;
          }
        }
      } else {
        if (t > 0) {
          switch (wid) {
            case 8:  lstm_wave<1,0>(AHBq_, DHBp_, numq, s_invden, pand, l, xs, z0, z1); break;
            case 9:  lstm_wave<1,1>(AHBq_, DHBp_, numq, s_invden, pand, l, xs, z0, z1); break;
            case 10: lstm_wave<1,2>(AHBq_, DHBp_, numq, s_invden, pand, l, xs, z0, z1); break;
            case 11: lstm_wave<1,3>(AHBq_, DHBp_, numq, s_invden, pand, l, xs, z0, z1); break;
            case 12: lstm_wave<1,4>(AHBq_, DHBp_, numq, s_invden, pand, l, xs, z0, z1); break;
            case 13: lstm_wave<1,5>(AHBq_, DHBp_, numq, s_invden, pand, l, xs, z0, z1); break;
            case 14: lstm_wave<1,6>(AHBq_, DHBp_, numq, s_invden, pand, l, xs, z0, z1); break;
            default: lstm_wave<1,7>(AHBq_, DHBp_, numq, s_invden, pand, l, xs, z0, z1); break;
          }
        }
      }
      __syncthreads();   // staging LDS dead; overlay with zred
      if (wid < 8) {
        *reinterpret_cast<fvec4*>(&sm.u.x2.zra[wid][0][l][0]) = z0;
        *reinterpret_cast<fvec4*>(&sm.u.x2.zra[wid][1][l][0]) = z1;
      } else {
        *reinterpret_cast<fvec4*>(&sm.u.x2.zrd[wid - 8][0][l][0]) = z0;
        *reinterpret_cast<fvec4*>(&sm.u.x2.zrd[wid - 8][1][l][0]) = z1;
      }
    }
    __syncthreads();
    if (tid < 256) {  // gate epilogue (8-way slice reduce)
      const int ls = tid >> 7, uu = (tid >> 5) & 3, b = tid & 31;
      const bool go = (ls == 0) ? (t < kT) : (t > 0);
      if (go) {
        const int mt = b >> 4, mm = b & 15;
        const int lane_base = (mm >> 2) * 16, rr = mm & 3;
        float zg[4];
        #pragma unroll
        for (int g = 0; g < 4; ++g) {
          int ln = lane_base + g * 4 + uu;
          float s = 0.f;
          if (ls == 0) {
            #pragma unroll
            for (int w = 0; w < 8; ++w) s += sm.u.x2.zra[w][mt][ln][rr];
          } else {
            #pragma unroll
            for (int w = 0; w < 8; ++w) s += sm.u.x2.zrd[w][mt][ln][rr];
          }
          int rg = g * 1024 + bk * 4 + uu;
          s += (ls ? dbih[rg] + dbhh[rg] : abih[rg] + abhh[rg]);
          zg[g] = s;
        }
        float* cst = ls ? DC : AC;
        const int idx = b * kArnn + bk * 4 + uu;
        float c = sigf(zg[1]) * cst[idx] + sigf(zg[0]) * tanhfast(zg[2]);
        cst[idx] = c;
        float h = sigf(zg[3]) * tanhfast(c);
        if (ls) asf(&DH[q * kB * kArnn + idx], h);
        sm.u.x2.hb[ls][b][uu] = h;
      }
    }
    __syncthreads();
    if (tid < 64) {  // pack h -> bf16 state
      int ls = tid >> 5, b = tid & 31;
      bool go2 = ls ? (t > 0) : (t < kT);
      if (go2) {
        U64u pk;
        #pragma unroll
        for (int j = 0; j < 4; ++j) pk.s[j] = bf16rn(sm.u.x2.hb[ls][b][j]);
        ushortt* dst = (ls ? (DHBu + q * kB * kArnn) : (AHBu + p * kB * kArnn)) + b * kArnn + bk * 4;
        as64(dst, pk.u);
      }
    }
    gbar_light(bar, ++bcnt, bk, tid);

    if (t < kT) {
      // ---- phase B: attention step t (+ mel/gate of t-1) ----
      const int b = bk >> 3, sub = bk & 7, j0 = sub * 64;
      const int pbase = (sub == 0) ? 0 : 21 + (sub - 1) * 20;
      const int pcnt = (sub == 0) ? 21 : 20;
      const ushortt* AHBp_ = AHBu + p * kB * kArnn;
      // S1: staging (pm/gmb are LDS-persistent; no per-step copy)
      if (tid < 256) {
        U64u v; v.u = ald64(AHBp_ + b * kArnn + tid * 4);
        #pragma unroll
        for (int j = 0; j < 4; ++j) sm.u.b.ahb_s[tid * 4 + j] = bf2f(v.s[j]);
      }
      for (int i = tid; i < 94; i += NTHR) {
        int jj = j0 - kPad + i;
        bool ok = (jj >= 0 && jj < kNctx);
        sm.u.b.aw_s[i] = ok ? alf(&AWp[b * kNctx + jj]) : 0.f;
        sm.u.b.awc_s[i] = ok ? alf(&AWC[b * kNctx + jj]) : 0.f;
      }
      for (int i = tid; i < kNF * 2 * kKS; i += NTHR) sm.u.b.cw[i] = cvw[i];
      for (int i = tid; i < kAdim * 33; i += NTHR) sm.u.b.lwt[i] = LWT[i];
      for (int i = tid; i < kAdim; i += NTHR) sm.u.b.vw_s[i] = vw[i];
      if (sub < 4 && t > 0) {
        for (int i = tid; i < kArnn + kEmb; i += NTHR)
          sm.u.b.dhc[i] = (i < kArnn) ? alf(&DH[q * kB * kArnn + b * kArnn + i])
                                      : alf(&ACTX[b * kEmb + (i - kArnn)]);
      }
      __syncthreads();
      // S2: q partial (8-way K split, contiguous bf16 weights)
      {
        int d = tid & 127, qr = tid >> 7;   // 0..7
        const ushortt* wq = QWTBu + (size_t)d * kArnn + qr * 128;
        const float* ahs = sm.u.b.ahb_s + qr * 128;
        float acc = 0.f;
        #pragma unroll 4
        for (int h8 = 0; h8 < 16; ++h8) {
          U64u a, c2;
          a.u = *reinterpret_cast<const u64*>(wq + h8 * 8);
          c2.u = *reinterpret_cast<const u64*>(wq + h8 * 8 + 4);
          #pragma unroll
          for (int j = 0; j < 4; ++j) acc = fmaf(bf2f(a.s[j]), ahs[h8 * 8 + j], acc);
          #pragma unroll
          for (int j = 0; j < 4; ++j) acc = fmaf(bf2f(c2.s[j]), ahs[h8 * 8 + 4 + j], acc);
        }
        sm.u.b.psum[tid] = acc;
      }
      __syncthreads();
      // S3: q reduce + conv + projection partials
      if (tid < kAdim) {
        float s = 0.f;
        #pragma unroll
        for (int k = 0; k < 8; ++k) s += sm.u.b.psum[tid + 128 * k];
        sm.u.b.q_s[tid] = s;
      }
      if (tid < 512) {
        int j = tid >> 3, f0 = (tid & 7) * 4;
        #pragma unroll
        for (int fi = 0; fi < 4; ++fi) {
          int f = f0 + fi;
          const float* w0 = &sm.u.b.cw[f * 62];
          float s = 0.f;
          for (int k = 0; k < kKS; ++k)
            s = fmaf(sm.u.b.aw_s[j + k], w0[k], fmaf(sm.u.b.awc_s[j + k], w0[31 + k], s));
          sm.u.b.loc_s[j * 33 + f] = s;
        }
      }
      if (sub < 4 && t > 0 && tid < pcnt * 6) {
        int ol = tid / 6, kc = tid % 6, og = pbase + ol;
        const float* row = (og < kNMel) ? pjw + (size_t)og * (kArnn + kEmb) : gw;
        const float* x = sm.u.b.dhc + kc * 256;
        const float* r2 = row + kc * 256;
        float acc = 0.f;
        for (int k = 0; k < 256; ++k) acc = fmaf(r2[k], x[k], acc);
        sm.u.b.pprj[tid] = acc;
      }
      __syncthreads();
      // S4: energies + exp; projection finals
      if (tid < 512) {
        int j = tid >> 3, grp = tid & 7, jj = j0 + j;
        float pe = 0.f;
        #pragma unroll 4
        for (int dd = 0; dd < 16; ++dd) {
          int d = grp + 8 * dd;
          float l2 = 0.f;
          const float* ls2 = &sm.u.b.loc_s[j * 33];
          const float* lw2 = &sm.u.b.lwt[d * 33];
          #pragma unroll 8
          for (int f = 0; f < kNF; ++f) l2 = fmaf(ls2[f], lw2[f], l2);
          float x = sm.u.b.q_s[d] + bf2f(sm.pm[j * kAdim + d]) + l2;
          pe = fmaf(sm.u.b.vw_s[d], tanhfast(x), pe);
        }
        pe += __shfl_xor(pe, 1);
        pe += __shfl_xor(pe, 2);
        pe += __shfl_xor(pe, 4);
        if (grp == 0) {
          float pv = mask[b * kNctx + jj] ? 0.f : __expf(pe);
          sm.u.b.p_s[j] = pv;
          PAW[b * kNctx + jj] = pv;   // block-private
        }
      }
      if (sub < 4 && t > 0 && tid < pcnt) {
        int og = pbase + tid;
        float val = (og < kNMel) ? pjb[og] : gb[0];
        #pragma unroll
        for (int kc = 0; kc < 6; ++kc) val += sm.u.b.pprj[tid * 6 + kc];
        if (og < kNMel) out[((size_t)b * kNMel + og) * kT + (t - 1)] = val;
        else out[(size_t)kB * kNMel * kT + b * kT + (t - 1)] = val;
      }
      __syncthreads();
      // S5: denominator + numerator (LDS-resident memory tile; single atomic/col)
      if (tid < 64) {
        float v = sm.u.b.p_s[tid];
        #pragma unroll
        for (int o = 1; o < 64; o <<= 1) v += __shfl_xor(v, o);
        if (tid == 0) atomicAdd(DEN + p * kB + b, v);
      }
      float nsum;
      {
        int col = tid & 511, half = tid >> 9;
        const ushortt* memb = sm.gmb + (size_t)(half * 32) * kEmb + col;
        float a0 = 0.f, a1 = 0.f, a2 = 0.f, a3 = 0.f;
        #pragma unroll 4
        for (int jj2 = 0; jj2 < 32; jj2 += 4) {
          a0 = fmaf(sm.u.b.p_s[half * 32 + jj2],     bf2f(memb[(size_t)jj2 * kEmb]), a0);
          a1 = fmaf(sm.u.b.p_s[half * 32 + jj2 + 1], bf2f(memb[(size_t)(jj2 + 1) * kEmb]), a1);
          a2 = fmaf(sm.u.b.p_s[half * 32 + jj2 + 2], bf2f(memb[(size_t)(jj2 + 2) * kEmb]), a2);
          a3 = fmaf(sm.u.b.p_s[half * 32 + jj2 + 3], bf2f(memb[(size_t)(jj2 + 3) * kEmb]), a3);
        }
        nsum = (a0 + a1) + (a2 + a3);
        if (half) sm.u.b.psum[col] = nsum;
      }
      __syncthreads();
      if (tid < 512) atomicAdd(&nump[b * kEmb + tid], nsum + sm.u.b.psum[tid]);
      gbar_light(bar, ++bcnt, bk, tid);
    }
  }

  // final projection t=499 (dh parity 1; ACTX(499) finalized in phase X(500))
  if (bk < kB) {
    const int b = bk;
    for (int i = tid; i < kArnn + kEmb; i += NTHR)
      sm.u.b.dhc[i] = (i < kArnn) ? alf(&DH[1 * kB * kArnn + b * kArnn + i])
                                  : alf(&ACTX[b * kEmb + (i - kArnn)]);
    __syncthreads();
    if (tid < 486) {
      int ol = tid / 6, kc = tid % 6;
      const float* row = (ol < kNMel) ? pjw + (size_t)ol * (kArnn + kEmb) : gw;
      const float* x = sm.u.b.dhc + kc * 256;
      const float* r2 = row + kc * 256;
      float acc = 0.f;
      for (int k = 0; k < 256; ++k) acc = fmaf(r2[k], x[k], acc);
      sm.u.b.psum[tid] = acc;
    }
    __syncthreads();
    if (tid < 81) {
      float val = (tid < kNMel) ? pjb[tid] : gb[0];
      #pragma unroll
      for (int kc = 0; kc < 6; ++kc) val += sm.u.b.psum[tid * 6 + kc];
      if (tid < kNMel) out[((size_t)b * kNMel + tid) * kT + (kT - 1)] = val;
      else out[(size_t)kB * kNMel * kT + b * kT + (kT - 1)] = val;
    }
  }
}

extern "C" void kernel_launch(void* const* d_in, const int* in_sizes, int n_in,
                              void* d_out, int out_size, void* d_ws, size_t ws_size,
                              hipStream_t stream) {
  const float* gmem = (const float*)d_in[0];
  const float* dec = (const float*)d_in[1];
  const unsigned char* mask = (const unsigned char*)d_in[2];
  const float* pw1 = (const float*)d_in[3];
  const float* pw2 = (const float*)d_in[4];
  const float* awih = (const float*)d_in[5];
  const float* awhh = (const float*)d_in[6];
  const float* abih = (const float*)d_in[7];
  const float* abhh = (const float*)d_in[8];
  const float* qw = (const float*)d_in[9];
  const float* mw = (const float*)d_in[10];
  const float* cvw = (const float*)d_in[11];
  const float* locw = (const float*)d_in[12];
  const float* vw = (const float*)d_in[13];
  const float* dwih = (const float*)d_in[14];
  const float* dwhh = (const float*)d_in[15];
  const float* dbih = (const float*)d_in[16];
  const float* dbhh = (const float*)d_in[17];
  const float* pjw = (const float*)d_in[18];
  const float* pjb = (const float*)d_in[19];
  const float* gw = (const float*)d_in[20];
  const float* gb = (const float*)d_in[21];
  float* out = (float*)d_out;
  float* ws = (float*)d_ws;

  // entire barrier region (flags + wake lines + init barrier) must start at 0
  hipMemsetAsync((char*)d_ws + (size_t)OFF_BAR * sizeof(float), 0,
                 (size_t)BAR_LINES * 128, stream);
  hipLaunchKernelGGL(decoder_kernel, dim3(NBLK), dim3(NTHR), 0, stream,
                     gmem, dec, mask, pw1, pw2, awih, awhh, abih, abhh, qw, mw,
                     cvw, locw, vw, dwih, dwhh, dbih, dbhh, pjw, pjb, gw, gb,
                     out, ws);
}

// Round 14
// 38800.491 us; speedup vs baseline: 1.1153x; 1.0970x over previous
//
#include <hip/hip_runtime.h>

#define NBLK 256
#define NTHR 512

constexpr int kNMel = 80, kArnn = 1024, kAdim = 128, kEmb = 512, kPre = 256;
constexpr int kNF = 32, kKS = 31, kB = 32, kNctx = 512, kT = 500, kPad = 15;

constexpr int KT_A = 56;   // 1792/32 k-tiles (aLSTM: 256 prenet + 512 actx + 1024 ah)
constexpr int KT_D = 80;   // 2560/32 k-tiles (dLSTM: 1024 ah + 512 actx + 1024 dh)
constexpr int KT_ALL = KT_A + KT_D;

// ---- workspace layout (float offsets); GMB last so it is optional ----
constexpr int OFF_PREB   = 0;                                    // bf16 [500][32][256]
constexpr int OFF_PROCMB = OFF_PREB + kT * kB * kPre / 2;        // bf16 [32*512][128]
constexpr int OFF_QWTB   = OFF_PROCMB + kB * kNctx * kAdim / 2;  // bf16 [128][1024]
constexpr int OFF_LWT    = OFF_QWTB + kAdim * kArnn / 2;         // f32 [128*33]
constexpr int OFF_STATE  = OFF_LWT + kAdim * 33;
constexpr int OFF_AHB    = OFF_STATE;                            // bf16 [2][32][1024]
constexpr int OFF_DHB    = OFF_AHB + 2 * kB * kArnn / 2;         // bf16 [2][32][1024]
constexpr int OFF_DH     = OFF_DHB + 2 * kB * kArnn / 2;         // f32 [2][32][1024]
constexpr int OFF_AC     = OFF_DH + 2 * kB * kArnn;              // f32 [32][1024]
constexpr int OFF_DC     = OFF_AC + kB * kArnn;
constexpr int OFF_ACTX   = OFF_DC + kB * kArnn;                  // f32 [32][512]
constexpr int OFF_AW     = OFF_ACTX + kB * kEmb;                 // f32 [32][512]
constexpr int OFF_AWC    = OFF_AW + kB * kNctx;
constexpr int OFF_PAW    = OFF_AWC + kB * kNctx;                 // block-private
constexpr int OFF_NUM    = OFF_PAW + kB * kNctx;                 // f32 [2][32][512]
constexpr int OFF_DEN    = OFF_NUM + 2 * kB * kEmb;              // f32 [2][32]
constexpr int OFF_END    = OFF_DEN + 2 * kB;
constexpr int STATE_SZ   = OFF_END - OFF_STATE;
// barrier region: one 128B line per word (per-block flags, wake replicas, init)
constexpr int OFF_BAR    = OFF_END;
constexpr int BAR_LINES  = 266;
constexpr int OFF_PAN    = OFF_BAR + BAR_LINES * 32;             // bf16 panels
constexpr int PAN_SZ     = NBLK * KT_ALL * 256;                  // floats
constexpr int OFF_GMB    = OFF_PAN + PAN_SZ;                     // bf16 [32*512][512] (optional)
constexpr int GMB_SZ     = kB * kNctx * kEmb / 2;

typedef __attribute__((ext_vector_type(4))) float fvec4;
typedef __attribute__((ext_vector_type(8))) short bh8_t;
typedef unsigned long long u64;
typedef unsigned short ushortt;

union U64u { u64 u; float2 f2; ushortt s[4]; };

union SMem {
  struct { ushortt xs[8][2][2048]; } x1;                             // 64 KB staging
  struct { float zra[4][2][64][4]; float zrd[4][2][64][4];
           float hb[2][32][4]; } x2;                                 // overlay after staging dead
  struct { float ahb_s[kArnn]; float vw_s[kAdim]; float psum[512]; float q_s[kAdim];
           float aw_s[96]; float awc_s[96]; float cw[kNF * 2 * kKS];
           float loc_s[64 * 33]; float p_s[64]; float lwt[kAdim * 33];
           float dhc[kArnn + kEmb]; float pprj[126];
           ushortt pm[64 * kAdim]; } b;
  struct { float x8[8][80]; float h1[8][256]; } p;
  struct { float mem_s[4][512]; } m;
};

__device__ __forceinline__ float sigf(float x) { return 1.0f / (1.0f + __expf(-x)); }
__device__ __forceinline__ float tanhfast(float x) { return 1.0f - 2.0f / (__expf(2.0f * x) + 1.0f); }

__device__ __forceinline__ ushortt bf16rn(float f) {
  unsigned u = __float_as_uint(f);
  unsigned r = (u + 0x7FFFu + ((u >> 16) & 1u)) >> 16;
  return (ushortt)r;
}
__device__ __forceinline__ float bf2f(ushortt v) {
  return __uint_as_float((unsigned)v << 16);
}

// relaxed agent-scope atomics: cross-XCD coherent, no cache-invalidation side effects
__device__ __forceinline__ u64 ald64(const void* p) {
  return __hip_atomic_load((const u64*)p, __ATOMIC_RELAXED, __HIP_MEMORY_SCOPE_AGENT);
}
__device__ __forceinline__ float alf(const float* p) {
  return __hip_atomic_load(p, __ATOMIC_RELAXED, __HIP_MEMORY_SCOPE_AGENT);
}
__device__ __forceinline__ void asf(float* p, float v) {
  __hip_atomic_store(p, v, __ATOMIC_RELAXED, __HIP_MEMORY_SCOPE_AGENT);
}
__device__ __forceinline__ void as64(void* p, u64 v) {
  __hip_atomic_store((u64*)p, v, __ATOMIC_RELAXED, __HIP_MEMORY_SCOPE_AGENT);
}
__device__ __forceinline__ unsigned alu(const unsigned* p) {
  return __hip_atomic_load(p, __ATOMIC_RELAXED, __HIP_MEMORY_SCOPE_AGENT);
}
__device__ __forceinline__ void asu(unsigned* p, unsigned v) {
  __hip_atomic_store(p, v, __ATOMIC_RELAXED, __HIP_MEMORY_SCOPE_AGENT);
}

// heavyweight init barrier (acq/rel) — used twice, before the scan
__device__ __forceinline__ void gbar_full(unsigned* cnt, unsigned* gen, unsigned& genv) {
  __syncthreads();
  if (threadIdx.x == 0) {
    __threadfence();
    unsigned arrived = __hip_atomic_fetch_add(cnt, 1u, __ATOMIC_ACQ_REL, __HIP_MEMORY_SCOPE_AGENT) + 1u;
    if (arrived == (unsigned)NBLK) {
      __hip_atomic_store(cnt, 0u, __ATOMIC_RELAXED, __HIP_MEMORY_SCOPE_AGENT);
      __hip_atomic_fetch_add(gen, 1u, __ATOMIC_ACQ_REL, __HIP_MEMORY_SCOPE_AGENT);
    } else {
      while (__hip_atomic_load(gen, __ATOMIC_ACQUIRE, __HIP_MEMORY_SCOPE_AGENT) == genv) {
        __builtin_amdgcn_s_sleep(2);
      }
    }
    ++genv;
  }
  __syncthreads();
}

// lightweight scan barrier: per-block flag lines (no RMW, no shared-line contention).
__device__ __forceinline__ void gbar_light(unsigned* bar, unsigned target, int bk, int tid) {
  asm volatile("s_waitcnt vmcnt(0) lgkmcnt(0)" ::: "memory");
  __syncthreads();
  if (bk == 0) {
    if (tid < 64) {
      if (tid == 0) asm volatile("s_waitcnt vmcnt(0)" ::: "memory");
      unsigned i0 = (unsigned)tid * 4, i1 = i0 + 1, i2 = i0 + 2, i3 = i0 + 3;
      for (;;) {
        bool ok = true;
        if (i0 != 0) ok = ok && (alu(&bar[i0 * 32]) >= target);
        ok = ok && (alu(&bar[i1 * 32]) >= target);
        ok = ok && (alu(&bar[i2 * 32]) >= target);
        ok = ok && (alu(&bar[i3 * 32]) >= target);
        if (__all(ok)) break;
        __builtin_amdgcn_s_sleep(1);
      }
      if (tid < 8) asu(&bar[(256 + tid) * 32], target);
    }
  } else {
    if (tid == 0) {
      asm volatile("s_waitcnt vmcnt(0)" ::: "memory");
      asu(&bar[bk * 32], target);
      unsigned* wk = &bar[(256 + (bk & 7)) * 32];
      while (alu(wk) < target) __builtin_amdgcn_s_sleep(1);
    }
  }
  __syncthreads();
}

// ---- one wave's share of one LSTM step, double-buffered LDS staging + MFMA ----
// LS=0: aLSTM (7 chunks of 64 cols), LS=1: dLSTM (10 chunks). W = wave slot 0..3.
// actx cols are staged from numq (f32) scaled by 1/den per row.
template<int LS, int W>
__device__ __forceinline__ void lstm_wave(
    const ushortt* __restrict__ s0, const ushortt* __restrict__ s2,
    const float* __restrict__ numq, const float* __restrict__ invden,
    const short* __restrict__ pan,
    int l, ushortt* xstg, fvec4& z0, fvec4& z1)
{
  constexpr int NC  = LS ? 10 : 7;
  constexpr int CB  = LS ? W * 640 : W * 448;   // absolute col base of this wave
  constexpr int KT0 = LS ? W * 20 : W * 14;     // k-tile base
  constexpr int BD0 = LS ? 1024 : 256;          // end of s0 segment
  constexpr int BD1 = LS ? 1536 : 768;          // end of actx segment
  const int u8 = l & 15, rj = l >> 4;           // load mapping
  const int m = l & 15, kg = l >> 4;            // frag mapping

  u64 L0[8], L1[8];
  bh8_t f00, f01, f10, f11;

  auto load = [&](int c, u64* L, bh8_t& f0, bh8_t& f1) {
    const int c0 = CB + c * 64;                  // compile-time after unroll
    if (c0 >= BD0 && c0 < BD1) {                 // actx segment: f32 num, scale
      const float* base = numq + (c0 - BD0) + u8 * 4;
      #pragma unroll
      for (int j = 0; j < 8; ++j) {
        int row = 4 * j + rj;
        const float* fp = base + (size_t)row * kEmb;
        U64u a, b2; a.u = ald64(fp); b2.u = ald64(fp + 2);
        float s = invden[row];
        U64u pk;
        pk.s[0] = bf16rn(a.f2.x * s);  pk.s[1] = bf16rn(a.f2.y * s);
        pk.s[2] = bf16rn(b2.f2.x * s); pk.s[3] = bf16rn(b2.f2.y * s);
        L[j] = pk.u;
      }
    } else {
      const ushortt* bsrc; int stride; bool coh;
      if (c0 < BD0) { bsrc = s0 + c0;       stride = (LS ? 1024 : 256); coh = (LS == 1); }
      else          { bsrc = s2 + c0 - BD1; stride = 1024;              coh = true; }
      #pragma unroll
      for (int j = 0; j < 8; ++j) {
        const ushortt* ap = bsrc + (size_t)(4 * j + rj) * stride + u8 * 4;
        L[j] = coh ? ald64(ap) : *reinterpret_cast<const u64*>(ap);
      }
    }
    f0 = *reinterpret_cast<const bh8_t*>(pan + (size_t)(KT0 + c * 2) * 512 + l * 8);
    f1 = *reinterpret_cast<const bh8_t*>(pan + (size_t)(KT0 + c * 2 + 1) * 512 + l * 8);
  };
  auto stash = [&](int buf, u64* L) {
    #pragma unroll
    for (int j = 0; j < 8; ++j) {
      int row = 4 * j + rj;
      int sw = u8 ^ ((row & 7) << 1);
      *reinterpret_cast<u64*>(xstg + buf * 2048 + row * 64 + sw * 4) = L[j];
    }
  };
  auto consume = [&](int buf, bh8_t f0, bh8_t f1) {
    #pragma unroll
    for (int kt = 0; kt < 2; ++kt) {
      int sw = (2 * (kt * 4 + kg)) ^ ((m & 7) << 1);
      bh8_t a0 = *reinterpret_cast<const bh8_t*>(xstg + buf * 2048 + m * 64 + sw * 4);
      bh8_t a1 = *reinterpret_cast<const bh8_t*>(xstg + buf * 2048 + (16 + m) * 64 + sw * 4);
      bh8_t f = kt ? f1 : f0;
      z0 = __builtin_amdgcn_mfma_f32_16x16x32_bf16(a0, f, z0, 0, 0, 0);
      z1 = __builtin_amdgcn_mfma_f32_16x16x32_bf16(a1, f, z1, 0, 0, 0);
    }
  };

  load(0, L0, f00, f01);
  #pragma unroll
  for (int c = 0; c < NC; c += 2) {
    stash(0, L0);
    if (c + 1 < NC) load(c + 1, L1, f10, f11);
    consume(0, f00, f01);
    if (c + 1 < NC) {
      stash(1, L1);
      if (c + 2 < NC) load(c + 2, L0, f00, f01);
      consume(1, f10, f11);
    }
  }
}

extern "C" __global__ void __launch_bounds__(NTHR, 1)
decoder_kernel(const float* __restrict__ gmem, const float* __restrict__ dec,
               const unsigned char* __restrict__ mask,
               const float* __restrict__ pw1, const float* __restrict__ pw2,
               const float* __restrict__ awih, const float* __restrict__ awhh,
               const float* __restrict__ abih, const float* __restrict__ abhh,
               const float* __restrict__ qw, const float* __restrict__ mw,
               const float* __restrict__ cvw, const float* __restrict__ locw,
               const float* __restrict__ vw,
               const float* __restrict__ dwih, const float* __restrict__ dwhh,
               const float* __restrict__ dbih, const float* __restrict__ dbhh,
               const float* __restrict__ pjw, const float* __restrict__ pjb,
               const float* __restrict__ gw, const float* __restrict__ gb,
               float* __restrict__ out, float* __restrict__ ws, int useg)
{
  __shared__ SMem sm;
  __shared__ float s_invden[32];
  const int bk = blockIdx.x, tid = threadIdx.x;
  unsigned genv_f = 0, bcnt = 0;
  unsigned* bar = reinterpret_cast<unsigned*>(ws + OFF_BAR);
  unsigned* cntF = &bar[264 * 32];
  unsigned* genF = &bar[265 * 32];

  ushortt* PREBu = reinterpret_cast<ushortt*>(ws + OFF_PREB);
  ushortt* PROCMBu = reinterpret_cast<ushortt*>(ws + OFF_PROCMB);
  ushortt* QWTBu = reinterpret_cast<ushortt*>(ws + OFF_QWTB);
  float* LWT = ws + OFF_LWT;
  ushortt* AHBu = reinterpret_cast<ushortt*>(ws + OFF_AHB);
  ushortt* DHBu = reinterpret_cast<ushortt*>(ws + OFF_DHB);
  float* DH = ws + OFF_DH;
  float* AC = ws + OFF_AC;
  float* DC = ws + OFF_DC;
  float* ACTX = ws + OFF_ACTX;
  float* AWp = ws + OFF_AW;
  float* AWC = ws + OFF_AWC;
  float* PAW = ws + OFF_PAW;
  float* NUM = ws + OFF_NUM;
  float* DEN = ws + OFF_DEN;
  short* PANS = reinterpret_cast<short*>(ws + OFF_PAN);
  ushortt* GMB = reinterpret_cast<ushortt*>(ws + OFF_GMB);

  // ---------------- P0: zero state + QWTB + LWT ----------------
  for (int i = bk * NTHR + tid; i < STATE_SZ; i += NBLK * NTHR) (ws + OFF_STATE)[i] = 0.f;
  for (int i = bk * NTHR + tid; i < kAdim * kArnn; i += NBLK * NTHR)
    QWTBu[i] = bf16rn(qw[i]);
  for (int i = bk * NTHR + tid; i < kAdim * kNF; i += NBLK * NTHR) {
    int d = i >> 5, f = i & 31;
    LWT[d * 33 + f] = locw[i];
  }
  gbar_full(cntF, genF, genv_f);

  // ---------------- P1: den init, proc_mem (+bf16 gmem copy), prenet, panels ----------------
  if (bk == 0 && tid < 2 * kB) asf(&DEN[tid], 1.0f);
  for (int it = 0; it < 16; ++it) {
    int task0 = bk * 64 + it * 4;
    for (int i = tid; i < 2048; i += NTHR) {
      int pr = i >> 9, h = i & 511;
      sm.m.mem_s[pr][h] = gmem[(size_t)(task0 + pr) * kEmb + h];
    }
    __syncthreads();
    {
      int pr = tid >> 7, d = tid & 127;
      const float* mwr = mw + d * kEmb;
      float acc = 0.f;
      for (int h = 0; h < kEmb; ++h) acc = fmaf(sm.m.mem_s[pr][h], mwr[h], acc);
      PROCMBu[(size_t)(task0 + pr) * kAdim + d] = bf16rn(acc);
    }
    if (useg) {
      for (int i = tid; i < 2048; i += NTHR) {
        int pr = i >> 9, h = i & 511;
        GMB[(size_t)(task0 + pr) * kEmb + h] = bf16rn(sm.m.mem_s[pr][h]);
      }
    }
    __syncthreads();
  }
  for (int g = bk; g < 2000; g += NBLK) {
    int t_idx = g >> 2;
    int b0 = (g & 3) * 8;
    if (t_idx == 0) {
      for (int i = tid; i < 8 * kPre; i += NTHR)
        PREBu[(size_t)(b0 + (i >> 8)) * kPre + (i & 255)] = 0;
      continue;
    }
    for (int i = tid; i < 640; i += NTHR) {
      int bb = i / 80, m2 = i % 80;
      sm.p.x8[bb][m2] = dec[((size_t)(b0 + bb) * kNMel + m2) * kT + (t_idx - 1)];
    }
    __syncthreads();
    {
      int u = tid & 255, rep = tid >> 8;
      float acc[4] = {0.f, 0.f, 0.f, 0.f};
      for (int m2 = 0; m2 < 80; ++m2) {
        float w = pw1[u * kNMel + m2];
        #pragma unroll
        for (int r = 0; r < 4; ++r) acc[r] = fmaf(w, sm.p.x8[rep * 4 + r][m2], acc[r]);
      }
      #pragma unroll
      for (int r = 0; r < 4; ++r) sm.p.h1[rep * 4 + r][u] = fmaxf(acc[r], 0.f);
    }
    __syncthreads();
    {
      int u = tid & 255, rep = tid >> 8;
      float acc[4] = {0.f, 0.f, 0.f, 0.f};
      for (int k = 0; k < kPre; ++k) {
        float w = pw2[u * kPre + k];
        #pragma unroll
        for (int r = 0; r < 4; ++r) acc[r] = fmaf(w, sm.p.h1[rep * 4 + r][k], acc[r]);
      }
      #pragma unroll
      for (int r = 0; r < 4; ++r)
        PREBu[((size_t)t_idx * kB + b0 + rep * 4 + r) * kPre + u] = bf16rn(fmaxf(acc[r], 0.f));
    }
    __syncthreads();
  }
  {  // pack per-block bf16 weight panels in MFMA B-fragment order
    const int UNITS = NBLK * KT_ALL * 64;
    for (int u = bk * NTHR + tid; u < UNITS; u += NBLK * NTHR) {
      int bkk = u / (KT_ALL * 64);
      int rem = u - bkk * (KT_ALL * 64);
      int kta = rem >> 6, l = rem & 63;
      int lstm = (kta >= KT_A);
      int kt = lstm ? kta - KT_A : kta;
      int n = l & 15, kg = l >> 4;
      int r = (n >> 2) * 1024 + bkk * 4 + (n & 3);
      bh8_t v;
      #pragma unroll
      for (int j = 0; j < 8; ++j) {
        int k = kt * 32 + kg * 8 + j;
        float wv;
        if (!lstm) wv = (k < 768) ? awih[(size_t)r * 768 + k] : awhh[(size_t)r * 1024 + (k - 768)];
        else       wv = (k < 1536) ? dwih[(size_t)r * 1536 + k] : dwhh[(size_t)r * 1024 + (k - 1536)];
        v[j] = (short)bf16rn(wv);
      }
      *reinterpret_cast<bh8_t*>(PANS + (size_t)u * 8) = v;
    }
  }
  gbar_full(cntF, genF, genv_f);

  const short* pana = PANS + (size_t)bk * (KT_ALL * 512);
  const short* pand = pana + KT_A * 512;

  // ---------------- main scan: 2 barriers/step ----------------
  for (int t = 0; t <= kT; ++t) {
    const int p = t & 1, q = p ^ 1;
    float* nump = NUM + p * kB * kEmb;
    const float* numq = NUM + q * kB * kEmb;

    // ---- phase X: finalize(t-1) + aLSTM(t) + dLSTM(t-1) ----
    if (tid < kB) s_invden[tid] = 1.0f / alf(DEN + q * kB + tid);
    __syncthreads();
    if (t > 0 && tid < 64) {   // finalize step t-1 attention (own 64 elements)
      int idx = bk * 64 + tid;
      int b2 = idx >> 9;
      float invd = s_invden[b2];
      float av = PAW[idx] * invd;          // PAW block-private (plain)
      asf(&AWp[idx], av);
      asf(&AWC[idx], alf(&AWC[idx]) + av);
      asf(&ACTX[idx], alf(&numq[idx]) * invd);
    }
    if (t < kT) {
      if (tid < 64) asf(&nump[bk * 64 + tid], 0.f);
      if (bk == 0 && tid < kB) asf(DEN + p * kB + tid, 0.f);
    }
    {
      const int w8 = tid >> 6, l = tid & 63;
      fvec4 z0 = {0.f, 0.f, 0.f, 0.f}, z1 = z0;
      const ushortt* AHBq_ = AHBu + q * kB * kArnn;
      const ushortt* DHBp_ = DHBu + p * kB * kArnn;
      const ushortt* preb_t = PREBu + (size_t)t * kB * kPre;
      ushortt* xst = &sm.x1.xs[w8][0][0];
      const short* panb = PANS + (size_t)bk * (KT_ALL * 512);
      const short* pand2 = panb + KT_A * 512;
      if (w8 < 4) {
        if (t < kT) {
          switch (w8) {
            case 0: lstm_wave<0,0>(preb_t, AHBq_, numq, s_invden, panb, l, xst, z0, z1); break;
            case 1: lstm_wave<0,1>(preb_t, AHBq_, numq, s_invden, panb, l, xst, z0, z1); break;
            case 2: lstm_wave<0,2>(preb_t, AHBq_, numq, s_invden, panb, l, xst, z0, z1); break;
            default: lstm_wave<0,3>(preb_t, AHBq_, numq, s_invden, panb, l, xst, z0, z1); break;
          }
        }
      } else {
        if (t > 0) {
          switch (w8) {
            case 4: lstm_wave<1,0>(AHBq_, DHBp_, numq, s_invden, pand2, l, xst, z0, z1); break;
            case 5: lstm_wave<1,1>(AHBq_, DHBp_, numq, s_invden, pand2, l, xst, z0, z1); break;
            case 6: lstm_wave<1,2>(AHBq_, DHBp_, numq, s_invden, pand2, l, xst, z0, z1); break;
            default: lstm_wave<1,3>(AHBq_, DHBp_, numq, s_invden, pand2, l, xst, z0, z1); break;
          }
        }
      }
      __syncthreads();   // staging LDS dead; overlay with zred
      if (w8 < 4) {
        *reinterpret_cast<fvec4*>(&sm.x2.zra[w8][0][l][0]) = z0;
        *reinterpret_cast<fvec4*>(&sm.x2.zra[w8][1][l][0]) = z1;
      } else {
        *reinterpret_cast<fvec4*>(&sm.x2.zrd[w8 - 4][0][l][0]) = z0;
        *reinterpret_cast<fvec4*>(&sm.x2.zrd[w8 - 4][1][l][0]) = z1;
      }
    }
    __syncthreads();
    if (tid < 256) {  // gate epilogue
      const int ls = tid >> 7, uu = (tid >> 5) & 3, b = tid & 31;
      const bool go = (ls == 0) ? (t < kT) : (t > 0);
      if (go) {
        const int mt = b >> 4, mm = b & 15;
        const int lane_base = (mm >> 2) * 16, rr = mm & 3;
        float zg[4];
        #pragma unroll
        for (int g = 0; g < 4; ++g) {
          int ln = lane_base + g * 4 + uu;
          float s;
          if (ls == 0)
            s = sm.x2.zra[0][mt][ln][rr] + sm.x2.zra[1][mt][ln][rr]
              + sm.x2.zra[2][mt][ln][rr] + sm.x2.zra[3][mt][ln][rr];
          else
            s = sm.x2.zrd[0][mt][ln][rr] + sm.x2.zrd[1][mt][ln][rr]
              + sm.x2.zrd[2][mt][ln][rr] + sm.x2.zrd[3][mt][ln][rr];
          int rg = g * 1024 + bk * 4 + uu;
          s += (ls ? dbih[rg] + dbhh[rg] : abih[rg] + abhh[rg]);
          zg[g] = s;
        }
        float* cst = ls ? DC : AC;
        const int idx = b * kArnn + bk * 4 + uu;
        float c = sigf(zg[1]) * cst[idx] + sigf(zg[0]) * tanhfast(zg[2]);
        cst[idx] = c;
        float h = sigf(zg[3]) * tanhfast(c);
        if (ls) asf(&DH[q * kB * kArnn + idx], h);
        sm.x2.hb[ls][b][uu] = h;
      }
    }
    __syncthreads();
    if (tid < 64) {  // pack h -> bf16 state
      int ls = tid >> 5, b = tid & 31;
      bool go2 = ls ? (t > 0) : (t < kT);
      if (go2) {
        U64u pk;
        #pragma unroll
        for (int j = 0; j < 4; ++j) pk.s[j] = bf16rn(sm.x2.hb[ls][b][j]);
        ushortt* dst = (ls ? (DHBu + q * kB * kArnn) : (AHBu + p * kB * kArnn)) + b * kArnn + bk * 4;
        as64(dst, pk.u);
      }
    }
    gbar_light(bar, ++bcnt, bk, tid);

    if (t < kT) {
      // ---- phase B: attention step t (+ mel/gate of t-1) ----
      const int b = bk >> 3, sub = bk & 7, j0 = sub * 64;
      const int pbase = (sub == 0) ? 0 : 21 + (sub - 1) * 20;
      const int pcnt = (sub == 0) ? 21 : 20;
      const ushortt* AHBp_ = AHBu + p * kB * kArnn;
      // S1: staging
      if (tid < 256) {
        U64u v; v.u = ald64(AHBp_ + b * kArnn + tid * 4);
        #pragma unroll
        for (int j = 0; j < 4; ++j) sm.b.ahb_s[tid * 4 + j] = bf2f(v.s[j]);
      }
      for (int i = tid; i < 94; i += NTHR) {
        int jj = j0 - kPad + i;
        bool ok = (jj >= 0 && jj < kNctx);
        sm.b.aw_s[i] = ok ? alf(&AWp[b * kNctx + jj]) : 0.f;
        sm.b.awc_s[i] = ok ? alf(&AWC[b * kNctx + jj]) : 0.f;
      }
      for (int i = tid; i < kNF * 2 * kKS; i += NTHR) sm.b.cw[i] = cvw[i];
      for (int i = tid; i < kAdim * 33; i += NTHR) sm.b.lwt[i] = LWT[i];
      for (int i = tid; i < kAdim; i += NTHR) sm.b.vw_s[i] = vw[i];
      {  // proc_mem tile (bf16)
        const fvec4* src = reinterpret_cast<const fvec4*>(PROCMBu + (size_t)(b * kNctx + j0) * kAdim);
        fvec4* dst = reinterpret_cast<fvec4*>(sm.b.pm);
        for (int i = tid; i < 1024; i += NTHR) dst[i] = src[i];
      }
      if (sub < 4 && t > 0) {
        for (int i = tid; i < kArnn + kEmb; i += NTHR)
          sm.b.dhc[i] = (i < kArnn) ? alf(&DH[q * kB * kArnn + b * kArnn + i])
                                    : alf(&ACTX[b * kEmb + (i - kArnn)]);
      }
      __syncthreads();
      // S2: q partial (4-way K split, contiguous bf16 weights)
      {
        int d = tid & 127, qr = tid >> 7;
        const ushortt* wq = QWTBu + (size_t)d * kArnn + qr * 256;
        const float* ahs = sm.b.ahb_s + qr * 256;
        float acc = 0.f;
        #pragma unroll 4
        for (int h8 = 0; h8 < 32; ++h8) {
          U64u a, c2;
          a.u = *reinterpret_cast<const u64*>(wq + h8 * 8);
          c2.u = *reinterpret_cast<const u64*>(wq + h8 * 8 + 4);
          #pragma unroll
          for (int j = 0; j < 4; ++j) acc = fmaf(bf2f(a.s[j]), ahs[h8 * 8 + j], acc);
          #pragma unroll
          for (int j = 0; j < 4; ++j) acc = fmaf(bf2f(c2.s[j]), ahs[h8 * 8 + 4 + j], acc);
        }
        sm.b.psum[tid] = acc;
      }
      __syncthreads();
      // S3: q reduce + conv + projection partials
      if (tid < kAdim)
        sm.b.q_s[tid] = sm.b.psum[tid] + sm.b.psum[128 + tid]
                      + sm.b.psum[256 + tid] + sm.b.psum[384 + tid];
      {
        int j = tid >> 3, f0 = (tid & 7) * 4;
        #pragma unroll
        for (int fi = 0; fi < 4; ++fi) {
          int f = f0 + fi;
          const float* w0 = &sm.b.cw[f * 62];
          float s = 0.f;
          for (int k = 0; k < kKS; ++k)
            s = fmaf(sm.b.aw_s[j + k], w0[k], fmaf(sm.b.awc_s[j + k], w0[31 + k], s));
          sm.b.loc_s[j * 33 + f] = s;
        }
      }
      if (sub < 4 && t > 0 && tid < pcnt * 6) {
        int ol = tid / 6, kc = tid % 6, og = pbase + ol;
        const float* row = (og < kNMel) ? pjw + (size_t)og * (kArnn + kEmb) : gw;
        const float* x = sm.b.dhc + kc * 256;
        const float* r2 = row + kc * 256;
        float acc = 0.f;
        for (int k = 0; k < 256; ++k) acc = fmaf(r2[k], x[k], acc);
        sm.b.pprj[tid] = acc;
      }
      __syncthreads();
      // S4: energies + exp; projection finals
      {
        int j = tid >> 3, grp = tid & 7, jj = j0 + j;
        float pe = 0.f;
        #pragma unroll 4
        for (int dd = 0; dd < 16; ++dd) {
          int d = grp + 8 * dd;
          float l2 = 0.f;
          const float* ls2 = &sm.b.loc_s[j * 33];
          const float* lw2 = &sm.b.lwt[d * 33];
          #pragma unroll 8
          for (int f = 0; f < kNF; ++f) l2 = fmaf(ls2[f], lw2[f], l2);
          float x = sm.b.q_s[d] + bf2f(sm.b.pm[j * kAdim + d]) + l2;
          pe = fmaf(sm.b.vw_s[d], tanhfast(x), pe);
        }
        pe += __shfl_xor(pe, 1);
        pe += __shfl_xor(pe, 2);
        pe += __shfl_xor(pe, 4);
        if (grp == 0) {
          float pv = mask[b * kNctx + jj] ? 0.f : __expf(pe);
          sm.b.p_s[j] = pv;
          PAW[b * kNctx + jj] = pv;   // block-private
        }
      }
      if (sub < 4 && t > 0 && tid < pcnt) {
        int og = pbase + tid;
        float val = (og < kNMel) ? pjb[og] : gb[0];
        #pragma unroll
        for (int kc = 0; kc < 6; ++kc) val += sm.b.pprj[tid * 6 + kc];
        if (og < kNMel) out[((size_t)b * kNMel + og) * kT + (t - 1)] = val;
        else out[(size_t)kB * kNMel * kT + b * kT + (t - 1)] = val;
      }
      __syncthreads();
      // S5: denominator + numerator (parity-p buffers)
      if (tid < 64) {
        float v = sm.b.p_s[tid];
        #pragma unroll
        for (int o = 1; o < 64; o <<= 1) v += __shfl_xor(v, o);
        if (tid == 0) atomicAdd(DEN + p * kB + b, v);
      }
      if (useg) {
        const ushortt* memb = GMB + (size_t)(b * kNctx + j0) * kEmb + tid;
        float a0 = 0.f, a1 = 0.f, a2 = 0.f, a3 = 0.f;
        #pragma unroll 4
        for (int jj2 = 0; jj2 < 64; jj2 += 4) {
          a0 = fmaf(sm.b.p_s[jj2],     bf2f(memb[(size_t)jj2 * kEmb]), a0);
          a1 = fmaf(sm.b.p_s[jj2 + 1], bf2f(memb[(size_t)(jj2 + 1) * kEmb]), a1);
          a2 = fmaf(sm.b.p_s[jj2 + 2], bf2f(memb[(size_t)(jj2 + 2) * kEmb]), a2);
          a3 = fmaf(sm.b.p_s[jj2 + 3], bf2f(memb[(size_t)(jj2 + 3) * kEmb]), a3);
        }
        atomicAdd(&nump[b * kEmb + tid], (a0 + a1) + (a2 + a3));
      } else {
        const float* memb = gmem + (size_t)(b * kNctx + j0) * kEmb + tid;
        float a0 = 0.f, a1 = 0.f;
        #pragma unroll 8
        for (int jj2 = 0; jj2 < 64; jj2 += 2) {
          a0 = fmaf(sm.b.p_s[jj2], memb[(size_t)jj2 * kEmb], a0);
          a1 = fmaf(sm.b.p_s[jj2 + 1], memb[(size_t)(jj2 + 1) * kEmb], a1);
        }
        atomicAdd(&nump[b * kEmb + tid], a0 + a1);
      }
      gbar_light(bar, ++bcnt, bk, tid);
    }
  }

  // final projection t=499 (dh parity 1; ACTX(499) finalized in phase X(500))
  if (bk < kB) {
    const int b = bk;
    for (int i = tid; i < kArnn + kEmb; i += NTHR)
      sm.b.dhc[i] = (i < kArnn) ? alf(&DH[1 * kB * kArnn + b * kArnn + i])
                                : alf(&ACTX[b * kEmb + (i - kArnn)]);
    __syncthreads();
    if (tid < 486) {
      int ol = tid / 6, kc = tid % 6;
      const float* row = (ol < kNMel) ? pjw + (size_t)ol * (kArnn + kEmb) : gw;
      const float* x = sm.b.dhc + kc * 256;
      const float* r2 = row + kc * 256;
      float acc = 0.f;
      for (int k = 0; k < 256; ++k) acc = fmaf(r2[k], x[k], acc);
      sm.b.psum[tid] = acc;
    }
    __syncthreads();
    if (tid < 81) {
      float val = (tid < kNMel) ? pjb[tid] : gb[0];
      #pragma unroll
      for (int kc = 0; kc < 6; ++kc) val += sm.b.psum[tid * 6 + kc];
      if (tid < kNMel) out[((size_t)b * kNMel + tid) * kT + (kT - 1)] = val;
      else out[(size_t)kB * kNMel * kT + b * kT + (kT - 1)] = val;
    }
  }
}

extern "C" void kernel_launch(void* const* d_in, const int* in_sizes, int n_in,
                              void* d_out, int out_size, void* d_ws, size_t ws_size,
                              hipStream_t stream) {
  const float* gmem = (const float*)d_in[0];
  const float* dec = (const float*)d_in[1];
  const unsigned char* mask = (const unsigned char*)d_in[2];
  const float* pw1 = (const float*)d_in[3];
  const float* pw2 = (const float*)d_in[4];
  const float* awih = (const float*)d_in[5];
  const float* awhh = (const float*)d_in[6];
  const float* abih = (const float*)d_in[7];
  const float* abhh = (const float*)d_in[8];
  const float* qw = (const float*)d_in[9];
  const float* mw = (const float*)d_in[10];
  const float* cvw = (const float*)d_in[11];
  const float* locw = (const float*)d_in[12];
  const float* vw = (const float*)d_in[13];
  const float* dwih = (const float*)d_in[14];
  const float* dwhh = (const float*)d_in[15];
  const float* dbih = (const float*)d_in[16];
  const float* dbhh = (const float*)d_in[17];
  const float* pjw = (const float*)d_in[18];
  const float* pjb = (const float*)d_in[19];
  const float* gw = (const float*)d_in[20];
  const float* gb = (const float*)d_in[21];
  float* out = (float*)d_out;
  float* ws = (float*)d_ws;

  int useg = (ws_size >= (size_t)(OFF_GMB + GMB_SZ) * sizeof(float)) ? 1 : 0;

  // entire barrier region (flags + wake lines + init barrier) must start at 0
  hipMemsetAsync((char*)d_ws + (size_t)OFF_BAR * sizeof(float), 0,
                 (size_t)BAR_LINES * 128, stream);
  hipLaunchKernelGGL(decoder_kernel, dim3(NBLK), dim3(NTHR), 0, stream,
                     gmem, dec, mask, pw1, pw2, awih, awhh, abih, abhh, qw, mw,
                     cvw, locw, vw, dwih, dwhh, dbih, dbhh, pjw, pjb, gw, gb,
                     out, ws, useg);
}